// Round 1
// baseline (6201.171 us; speedup 1.0000x reference)
//
#include <hip/hip_runtime.h>
#include <hip/hip_bf16.h>

typedef __hip_bfloat16 bf16;

#define SCALE 0.17677669529663687f

// ---- workspace offsets (bytes) ----
// qkv spatial (rolled coords), bf16 [B][768][256][256]
#define OFF_QKV   0ull
// squeeze out fp32 [B][128][256][256] (ch 0..63 = up64, 64..127 = low64)
#define OFF_UL    201326592ull
// cru pre-softmax out bf16 [B][512][256][256]
#define OFF_CRU   268435456ull
#define OFF_POOL  402653184ull   // fp32 [2][512] channel sums
#define OFF_GNACC 402657280ull   // fp32 [2][16][2] sum/sumsq
#define OFF_GNFIN 402657536ull   // fp32 [2][16][2] mu/rstd + [64]=1/sum(gn_w)
#define OFF_SOFT  402658048ull   // fp32 [2][512] softmax weights
#define OFF_WQT   402662144ull   // fp32 [256][768] w_qkv^T
#define OFF_WOT   403448576ull   // fp32 [256][256] w_out^T
// attention out bf16 [B][pix][256] — reuses UL region (dead by then)
#define OFF_ATTN  OFF_UL

__device__ __forceinline__ float b2f(bf16 v){ return __bfloat162float(v); }
__device__ __forceinline__ bf16  f2b(float v){ return __float2bfloat16(v); }

__device__ __forceinline__ float wave_sum64(float v){
  #pragma unroll
  for (int o = 32; o > 0; o >>= 1) v += __shfl_down(v, o);
  return v;
}

// ---------------- transpose of small weight matrices ----------------
__global__ void k_transpose(const float* __restrict__ in, float* __restrict__ out,
                            int R, int Ccols){
  int idx = blockIdx.x * 256 + threadIdx.x;
  if (idx < R * Ccols){
    int r = idx / Ccols, c = idx % Ccols;
    out[c * R + r] = in[idx];
  }
}

// ---------------- K1: qkv = x @ w_qkv^T + b (rolled coords) ----------------
// M=131072 pixels, N=768, K=256. 128x128 tile, 256 thr, 8x8/thread.
__global__ __launch_bounds__(256) void k_qkv_gemm(
    const float* __restrict__ x, const float* __restrict__ wT,
    const float* __restrict__ bias, bf16* __restrict__ qkv)
{
  __shared__ float As[16][132];
  __shared__ float Bs[16][132];
  int t = threadIdx.x;
  int tx = t & 15, ty = t >> 4;
  int m0 = blockIdx.x * 128, n0 = blockIdx.y * 128;
  float acc[8][8] = {};
  for (int k0 = 0; k0 < 256; k0 += 16){
    #pragma unroll
    for (int l = 0; l < 8; l++){
      int e = t + l * 256;
      int mm = e & 127, kk = e >> 7;
      int m = m0 + mm;
      int b = m >> 16, ij = m & 65535;
      int i = ij >> 8, j = ij & 255;
      int ir = (i + 4) & 255, jr = (j + 4) & 255;
      As[kk][mm] = x[(((size_t)(b * 256 + k0 + kk)) << 16) + (ir << 8) + jr];
    }
    #pragma unroll
    for (int l = 0; l < 8; l++){
      int e = t + l * 256;
      int nn = e & 127, kk = e >> 7;
      Bs[kk][nn] = wT[(size_t)(k0 + kk) * 768 + n0 + nn];
    }
    __syncthreads();
    #pragma unroll
    for (int kk = 0; kk < 16; kk++){
      float4 a0 = *(const float4*)&As[kk][ty * 4];
      float4 a1 = *(const float4*)&As[kk][64 + ty * 4];
      float4 b0 = *(const float4*)&Bs[kk][tx * 4];
      float4 b1 = *(const float4*)&Bs[kk][64 + tx * 4];
      float av[8] = {a0.x,a0.y,a0.z,a0.w,a1.x,a1.y,a1.z,a1.w};
      float bv[8] = {b0.x,b0.y,b0.z,b0.w,b1.x,b1.y,b1.z,b1.w};
      #pragma unroll
      for (int r = 0; r < 8; r++)
        #pragma unroll
        for (int c = 0; c < 8; c++) acc[r][c] += av[r] * bv[c];
    }
    __syncthreads();
  }
  #pragma unroll
  for (int r = 0; r < 8; r++){
    int mr = (r < 4) ? (ty * 4 + r) : (64 + ty * 4 + r - 4);
    int m = m0 + mr;
    int b = m >> 16, ij = m & 65535;
    #pragma unroll
    for (int c = 0; c < 8; c++){
      int nc = (c < 4) ? (tx * 4 + c) : (64 + tx * 4 + c - 4);
      int n = n0 + nc;
      qkv[(((size_t)(b * 768 + n)) << 16) + ij] = f2b(acc[r][c] + bias[n]);
    }
  }
}

// ---------------- K2a: GroupNorm partial stats over Q slice ----------------
__global__ __launch_bounds__(256) void k_gn_stats(const bf16* __restrict__ qkv,
                                                  float* __restrict__ acc)
{
  int blk = blockIdx.x;            // (b*16+g)*8 + s
  int s = blk & 7, bg = blk >> 3;
  int g = bg & 15, b = bg >> 4;
  int t = threadIdx.x;
  float sum = 0.f, sq = 0.f;
  for (int ch = 0; ch < 16; ch++){
    const bf16* base = qkv + (((size_t)(b * 768 + g * 16 + ch)) << 16) + s * 8192;
    for (int p = t; p < 8192; p += 256){
      float v = b2f(base[p]);
      sum += v; sq += v * v;
    }
  }
  __shared__ float rs[256], rq[256];
  rs[t] = sum; rq[t] = sq; __syncthreads();
  for (int st = 128; st > 0; st >>= 1){
    if (t < st){ rs[t] += rs[t + st]; rq[t] += rq[t + st]; }
    __syncthreads();
  }
  if (t == 0){
    atomicAdd(&acc[bg * 2], rs[0]);
    atomicAdd(&acc[bg * 2 + 1], rq[0]);
  }
}

__global__ __launch_bounds__(256) void k_gn_final(const float* __restrict__ acc,
                                                  const float* __restrict__ gn_w,
                                                  float* __restrict__ fin)
{
  __shared__ float red[256];
  int t = threadIdx.x;
  red[t] = gn_w[t]; __syncthreads();
  for (int st = 128; st > 0; st >>= 1){
    if (t < st) red[t] += red[t + st];
    __syncthreads();
  }
  if (t == 0) fin[64] = 1.0f / red[0];
  if (t < 32){
    const float Ninv = 1.0f / 1048576.0f;
    float mu = acc[t * 2] * Ninv;
    float var = acc[t * 2 + 1] * Ninv - mu * mu;
    fin[t * 2] = mu;
    fin[t * 2 + 1] = 1.0f / sqrtf(var + 1e-5f);
  }
}

// ---------------- K2b: SRU apply in-place on Q slice ----------------
__global__ __launch_bounds__(256) void k_sru(bf16* __restrict__ qkv,
    const float* __restrict__ fin, const float* __restrict__ gn_w,
    const float* __restrict__ gn_b)
{
  int idx = blockIdx.x * 256 + threadIdx.x;     // b(2)*c(128)*pix(65536)
  int pix = idx & 65535;
  int bc = idx >> 16;
  int c = bc & 127, b = bc >> 7;
  size_t i1 = (((size_t)(b * 768 + c)) << 16) + pix;
  size_t i2 = (((size_t)(b * 768 + c + 128)) << 16) + pix;
  float x1 = b2f(qkv[i1]);
  float x2 = b2f(qkv[i2]);
  int g1 = c >> 4, g2 = (c + 128) >> 4;
  float mu1 = fin[(b * 16 + g1) * 2], rs1 = fin[(b * 16 + g1) * 2 + 1];
  float mu2 = fin[(b * 16 + g2) * 2], rs2 = fin[(b * 16 + g2) * 2 + 1];
  float invs = fin[64];
  float w1c = gn_w[c], w2c = gn_w[c + 128];
  float gnx1 = (x1 - mu1) * rs1 * w1c + gn_b[c];
  float gnx2 = (x2 - mu2) * rs2 * w2c + gn_b[c + 128];
  float rw1 = 1.0f / (1.0f + __expf(-gnx1 * (w1c * invs)));
  float rw2 = 1.0f / (1.0f + __expf(-gnx2 * (w2c * invs)));
  float a1 = rw1 > 0.5f ? 1.0f : rw1, a2 = rw1 > 0.5f ? 0.0f : rw1;
  float b1 = rw2 > 0.5f ? 1.0f : rw2, b2v = rw2 > 0.5f ? 0.0f : rw2;
  qkv[i1] = f2b(a1 * x1 + b2v * x2);
  qkv[i2] = f2b(b1 * x2 + a2 * x1);
}

// ---------------- K3a: squeeze 1x1 convs on K slice -> ul ----------------
__global__ __launch_bounds__(256) void k_squeeze(const bf16* __restrict__ qkv,
    const float* __restrict__ sq1, const float* __restrict__ sq2,
    float* __restrict__ ul)
{
  __shared__ float in_s[128][65];
  int p0 = blockIdx.x * 64;
  int b = p0 >> 16, pl0 = p0 & 65535;
  int t = threadIdx.x;
  int pp = t & 63, og = t >> 6;      // og in 0..3, 16 outputs each
  // ---- up half (qkv ch 256..383) ----
  for (int e = t; e < 8192; e += 256){
    int ch = e >> 6, px = e & 63;
    in_s[ch][px] = b2f(qkv[(((size_t)(b * 768 + 256 + ch)) << 16) + pl0 + px]);
  }
  __syncthreads();
  {
    float acc[16] = {};
    for (int i = 0; i < 128; i++){
      float v = in_s[i][pp];
      #pragma unroll
      for (int o = 0; o < 16; o++) acc[o] += sq1[(og * 16 + o) * 128 + i] * v;
    }
    #pragma unroll
    for (int o = 0; o < 16; o++)
      ul[(((size_t)(b * 128 + og * 16 + o)) << 16) + pl0 + pp] = acc[o];
  }
  __syncthreads();
  // ---- low half (qkv ch 384..511) ----
  for (int e = t; e < 8192; e += 256){
    int ch = e >> 6, px = e & 63;
    in_s[ch][px] = b2f(qkv[(((size_t)(b * 768 + 384 + ch)) << 16) + pl0 + px]);
  }
  __syncthreads();
  {
    float acc[16] = {};
    for (int i = 0; i < 128; i++){
      float v = in_s[i][pp];
      #pragma unroll
      for (int o = 0; o < 16; o++) acc[o] += sq2[(og * 16 + o) * 128 + i] * v;
    }
    #pragma unroll
    for (int o = 0; o < 16; o++)
      ul[(((size_t)(b * 128 + 64 + og * 16 + o)) << 16) + pl0 + pp] = acc[o];
  }
}

// ---------------- K3b: CRU main (gwc3x3 grouped + pwc1, pwc2, copy) ----------------
__global__ __launch_bounds__(64) void k_cru_main(
    const float* __restrict__ ul, const float* __restrict__ gwc_w,
    const float* __restrict__ gwc_b, const float* __restrict__ pwc1,
    const float* __restrict__ pwc2, bf16* __restrict__ cru,
    float* __restrict__ pool)
{
  __shared__ float up_s[64][10][10];
  __shared__ float low_s[64][64];
  int b = blockIdx.z;
  int ty0 = blockIdx.y * 8, tx0 = blockIdx.x * 8;
  int t = threadIdx.x;
  for (int e = t; e < 6400; e += 64){
    int ch = e / 100, pos = e % 100;
    int yy = pos / 10, xx = pos % 10;
    int gi = ty0 - 1 + yy, gj = tx0 - 1 + xx;
    float v = 0.f;
    if (gi >= 0 && gi < 256 && gj >= 0 && gj < 256)
      v = ul[(((size_t)(b * 128 + ch)) << 16) + (gi << 8) + gj];
    up_s[ch][yy][xx] = v;
  }
  for (int e = t; e < 4096; e += 64){
    int ch = e >> 6, pp = e & 63;
    int yy = pp >> 3, xx = pp & 7;
    low_s[ch][pp] = ul[(((size_t)(b * 128 + 64 + ch)) << 16) + ((ty0 + yy) << 8) + (tx0 + xx)];
  }
  __syncthreads();
  int py = t >> 3, px = t & 7;
  int gpix = ((ty0 + py) << 8) + (tx0 + px);
  size_t obase = ((size_t)(b * 512)) << 16;
  // y1: 256 channels, blocks of 4
  for (int cb = 0; cb < 64; cb++){
    int c0 = cb * 4;
    int grp = c0 >> 7;
    float a0 = gwc_b[c0], a1 = gwc_b[c0+1], a2 = gwc_b[c0+2], a3 = gwc_b[c0+3];
    for (int i = 0; i < 32; i++){
      int ci = grp * 32 + i;
      #pragma unroll
      for (int dy = 0; dy < 3; dy++)
        #pragma unroll
        for (int dx = 0; dx < 3; dx++){
          float v = up_s[ci][py + dy][px + dx];
          int wi = i * 9 + dy * 3 + dx;
          a0 += gwc_w[(size_t)(c0    ) * 288 + wi] * v;
          a1 += gwc_w[(size_t)(c0 + 1) * 288 + wi] * v;
          a2 += gwc_w[(size_t)(c0 + 2) * 288 + wi] * v;
          a3 += gwc_w[(size_t)(c0 + 3) * 288 + wi] * v;
        }
    }
    for (int i = 0; i < 64; i++){
      float v = up_s[i][py + 1][px + 1];
      a0 += pwc1[(c0    ) * 64 + i] * v;
      a1 += pwc1[(c0 + 1) * 64 + i] * v;
      a2 += pwc1[(c0 + 2) * 64 + i] * v;
      a3 += pwc1[(c0 + 3) * 64 + i] * v;
    }
    float vals[4] = {a0, a1, a2, a3};
    #pragma unroll
    for (int u = 0; u < 4; u++){
      cru[obase + (((size_t)(c0 + u)) << 16) + gpix] = f2b(vals[u]);
      float ws = wave_sum64(vals[u]);
      if (t == 0) atomicAdd(&pool[b * 512 + c0 + u], ws);
    }
  }
  // y2a: pwc2 -> channels 256..447
  for (int cb = 0; cb < 48; cb++){
    int c0 = cb * 4;
    float a0 = 0.f, a1 = 0.f, a2 = 0.f, a3 = 0.f;
    for (int i = 0; i < 64; i++){
      float v = low_s[i][t];
      a0 += pwc2[(c0    ) * 64 + i] * v;
      a1 += pwc2[(c0 + 1) * 64 + i] * v;
      a2 += pwc2[(c0 + 2) * 64 + i] * v;
      a3 += pwc2[(c0 + 3) * 64 + i] * v;
    }
    float vals[4] = {a0, a1, a2, a3};
    #pragma unroll
    for (int u = 0; u < 4; u++){
      cru[obase + (((size_t)(256 + c0 + u)) << 16) + gpix] = f2b(vals[u]);
      float ws = wave_sum64(vals[u]);
      if (t == 0) atomicAdd(&pool[b * 512 + 256 + c0 + u], ws);
    }
  }
  // y2b: copy low -> channels 448..511
  for (int c = 0; c < 64; c++){
    float v = low_s[c][t];
    cru[obase + (((size_t)(448 + c)) << 16) + gpix] = f2b(v);
    float ws = wave_sum64(v);
    if (t == 0) atomicAdd(&pool[b * 512 + 448 + c], ws);
  }
}

// ---------------- K3f: channel softmax of pooled means ----------------
__global__ __launch_bounds__(512) void k_pool_softmax(const float* __restrict__ pool,
                                                      float* __restrict__ s)
{
  __shared__ float red[512];
  int t = threadIdx.x;
  for (int b = 0; b < 2; b++){
    float v = pool[b * 512 + t] * (1.0f / 65536.0f);
    red[t] = v; __syncthreads();
    for (int st = 256; st > 0; st >>= 1){
      if (t < st) red[t] = fmaxf(red[t], red[t + st]);
      __syncthreads();
    }
    float m = red[0]; __syncthreads();
    float e = __expf(v - m);
    red[t] = e; __syncthreads();
    for (int st = 256; st > 0; st >>= 1){
      if (t < st) red[t] += red[t + st];
      __syncthreads();
    }
    float inv = 1.0f / red[0];
    __syncthreads();
    s[b * 512 + t] = e * inv;
  }
}

// ---------------- K3c: k = s1*out1 + s2*out2 -> K slice of qkv ----------------
__global__ __launch_bounds__(256) void k_cru_apply(const bf16* __restrict__ cru,
    const float* __restrict__ s, bf16* __restrict__ qkv)
{
  int idx = blockIdx.x * 256 + threadIdx.x;  // b*256ch*65536pix
  int pix = idx & 65535;
  int bc = idx >> 16;
  int c = bc & 255, b = bc >> 8;
  float v1 = b2f(cru[(((size_t)(b * 512 + c)) << 16) + pix]);
  float v2 = b2f(cru[(((size_t)(b * 512 + 256 + c)) << 16) + pix]);
  float kv = s[b * 512 + c] * v1 + s[b * 512 + 256 + c] * v2;
  qkv[(((size_t)(b * 768 + 256 + c)) << 16) + pix] = f2b(kv);
}

// ---------------- K4: windowed attention ----------------
__global__ __launch_bounds__(64) void k_attn(const bf16* __restrict__ qkv,
    const float* __restrict__ rel_pos, bf16* __restrict__ attn)
{
  __shared__ float k_s[64][33];
  __shared__ float v_s[64][33];
  __shared__ float bias_s[225];
  int win = blockIdx.x, head = blockIdx.y, b = blockIdx.z;
  int hw = win >> 5, wwi = win & 31;
  int t = threadIdx.x;
  for (int e = t; e < 225; e += 64) bias_s[e] = rel_pos[head * 225 + e];
  int pi = t >> 3, pj = t & 7;
  int pix = ((hw * 8 + pi) << 8) | (wwi * 8 + pj);
  size_t base = ((size_t)(b * 768)) << 16;
  float q[32];
  #pragma unroll
  for (int d = 0; d < 32; d++){
    q[d]      = b2f(qkv[base + (((size_t)(      head * 32 + d)) << 16) + pix]);
    k_s[t][d] = b2f(qkv[base + (((size_t)(256 + head * 32 + d)) << 16) + pix]);
    v_s[t][d] = b2f(qkv[base + (((size_t)(512 + head * 32 + d)) << 16) + pix]);
  }
  __syncthreads();
  bool mH = (hw == 31), mW = (wwi == 31);
  float sim[64];
  float mx = -1e30f;
  #pragma unroll
  for (int j = 0; j < 64; j++){
    float sv = 0.f;
    #pragma unroll
    for (int d = 0; d < 32; d++) sv += q[d] * k_s[j][d];
    int ji = j >> 3, jj = j & 7;
    sv = sv * SCALE + bias_s[(pi - ji + 7) * 15 + (pj - jj + 7)];
    bool masked = (mH && ((pi < 4) != (ji < 4))) || (mW && ((pj < 4) != (jj < 4)));
    sv = masked ? -1e30f : sv;
    sim[j] = sv;
    mx = fmaxf(mx, sv);
  }
  float sum = 0.f;
  #pragma unroll
  for (int j = 0; j < 64; j++){
    float e = __expf(sim[j] - mx);
    sim[j] = e; sum += e;
  }
  float inv = 1.0f / sum;
  float o[32] = {};
  #pragma unroll
  for (int j = 0; j < 64; j++){
    float p = sim[j] * inv;
    #pragma unroll
    for (int d = 0; d < 32; d++) o[d] += p * v_s[j][d];
  }
  size_t ob = (((size_t)(b * 65536 + pix)) << 8) + head * 32;
  #pragma unroll
  for (int d = 0; d < 32; d++) attn[ob + d] = f2b(o[d]);
}

// ---------------- K6: out = attn @ w_out^T + b_out, roll back ----------------
__global__ __launch_bounds__(256) void k_proj(const bf16* __restrict__ attn,
    const float* __restrict__ wT, const float* __restrict__ bias,
    float* __restrict__ out)
{
  __shared__ float As[16][132];
  __shared__ float Bs[16][132];
  int t = threadIdx.x;
  int tx = t & 15, ty = t >> 4;
  int m0 = blockIdx.x * 128, n0 = blockIdx.y * 128;
  float acc[8][8] = {};
  for (int k0 = 0; k0 < 256; k0 += 16){
    #pragma unroll
    for (int l = 0; l < 8; l++){
      int e = t + l * 256;
      int mm = e >> 4, kk = e & 15;
      int m = m0 + mm;
      int b = m >> 16, ij = m & 65535;
      int i = ij >> 8, j = ij & 255;
      int ir = (i - 4) & 255, jr = (j - 4) & 255;
      As[kk][mm] = b2f(attn[(((size_t)(b * 65536) + (ir << 8) + jr) << 8) + k0 + kk]);
    }
    #pragma unroll
    for (int l = 0; l < 8; l++){
      int e = t + l * 256;
      int nn = e & 127, kk = e >> 7;
      Bs[kk][nn] = wT[(size_t)(k0 + kk) * 256 + n0 + nn];
    }
    __syncthreads();
    #pragma unroll
    for (int kk = 0; kk < 16; kk++){
      float4 a0 = *(const float4*)&As[kk][ty * 4];
      float4 a1 = *(const float4*)&As[kk][64 + ty * 4];
      float4 b0 = *(const float4*)&Bs[kk][tx * 4];
      float4 b1 = *(const float4*)&Bs[kk][64 + tx * 4];
      float av[8] = {a0.x,a0.y,a0.z,a0.w,a1.x,a1.y,a1.z,a1.w};
      float bv[8] = {b0.x,b0.y,b0.z,b0.w,b1.x,b1.y,b1.z,b1.w};
      #pragma unroll
      for (int r = 0; r < 8; r++)
        #pragma unroll
        for (int c = 0; c < 8; c++) acc[r][c] += av[r] * bv[c];
    }
    __syncthreads();
  }
  #pragma unroll
  for (int r = 0; r < 8; r++){
    int mr = (r < 4) ? (ty * 4 + r) : (64 + ty * 4 + r - 4);
    int m = m0 + mr;
    int b = m >> 16, ij = m & 65535;
    #pragma unroll
    for (int c = 0; c < 8; c++){
      int nc = (c < 4) ? (tx * 4 + c) : (64 + tx * 4 + c - 4);
      int n = n0 + nc;
      out[(((size_t)(b * 256 + n)) << 16) + ij] = acc[r][c] + bias[n];
    }
  }
}

extern "C" void kernel_launch(void* const* d_in, const int* in_sizes, int n_in,
                              void* d_out, int out_size, void* d_ws, size_t ws_size,
                              hipStream_t stream) {
  const float* x       = (const float*)d_in[0];
  const float* w_qkv   = (const float*)d_in[1];
  const float* b_qkv   = (const float*)d_in[2];
  const float* rel_pos = (const float*)d_in[3];
  const float* gn_w    = (const float*)d_in[4];
  const float* gn_b    = (const float*)d_in[5];
  const float* sq1     = (const float*)d_in[6];
  const float* sq2     = (const float*)d_in[7];
  const float* gwc_w   = (const float*)d_in[8];
  const float* gwc_b   = (const float*)d_in[9];
  const float* pwc1    = (const float*)d_in[10];
  const float* pwc2    = (const float*)d_in[11];
  const float* w_out   = (const float*)d_in[12];
  const float* b_out   = (const float*)d_in[13];
  float* out = (float*)d_out;

  char* ws = (char*)d_ws;
  bf16*  qkv   = (bf16*)(ws + OFF_QKV);
  float* ul    = (float*)(ws + OFF_UL);
  bf16*  cru   = (bf16*)(ws + OFF_CRU);
  float* pool  = (float*)(ws + OFF_POOL);
  float* gnacc = (float*)(ws + OFF_GNACC);
  float* gnfin = (float*)(ws + OFF_GNFIN);
  float* smax  = (float*)(ws + OFF_SOFT);
  float* wqkvT = (float*)(ws + OFF_WQT);
  float* woutT = (float*)(ws + OFF_WOT);
  bf16*  attn  = (bf16*)(ws + OFF_ATTN);

  hipMemsetAsync(ws + OFF_POOL, 0, 4096 + 256, stream);
  k_transpose<<<768, 256, 0, stream>>>(w_qkv, wqkvT, 768, 256);
  k_transpose<<<256, 256, 0, stream>>>(w_out, woutT, 256, 256);
  k_qkv_gemm<<<dim3(1024, 6), 256, 0, stream>>>(x, wqkvT, b_qkv, qkv);
  k_gn_stats<<<256, 256, 0, stream>>>(qkv, gnacc);
  k_gn_final<<<1, 256, 0, stream>>>(gnacc, gn_w, gnfin);
  k_sru<<<65536, 256, 0, stream>>>(qkv, gnfin, gn_w, gn_b);
  k_squeeze<<<2048, 256, 0, stream>>>(qkv, sq1, sq2, ul);
  k_cru_main<<<dim3(32, 32, 2), 64, 0, stream>>>(ul, gwc_w, gwc_b, pwc1, pwc2, cru, pool);
  k_pool_softmax<<<1, 512, 0, stream>>>(pool, smax);
  k_cru_apply<<<131072, 256, 0, stream>>>(cru, smax, qkv);
  k_attn<<<dim3(1024, 8, 2), 64, 0, stream>>>(qkv, rel_pos, attn);
  k_proj<<<dim3(1024, 2), 256, 0, stream>>>(attn, woutT, b_out, out);
}

// Round 2
// 3013.778 us; speedup vs baseline: 2.0576x; 2.0576x over previous
//
#include <hip/hip_runtime.h>
#include <hip/hip_bf16.h>

typedef __hip_bfloat16 bf16;

#define SCALE 0.17677669529663687f

// ---- workspace offsets (bytes) ----
// qkv spatial (rolled coords), bf16 [B][768][256][256]
#define OFF_QKV   0ull
// squeeze out fp32 [B][128][256][256] (ch 0..63 = up64, 64..127 = low64)
#define OFF_UL    201326592ull
// cru pre-softmax out bf16 [B][512][256][256]
#define OFF_CRU   268435456ull
#define OFF_POOL  402653184ull   // fp32 [2][512] channel sums
#define OFF_GNACC 402657280ull   // fp32 [2][16][2] sum/sumsq
#define OFF_GNFIN 402657536ull   // fp32 [2][16][2] mu/rstd + [64]=1/sum(gn_w)
#define OFF_SOFT  402658048ull   // fp32 [2][512] softmax weights
#define OFF_WQT   402662144ull   // fp32 [256][768] w_qkv^T (dead after qkv_gemm)
#define OFF_WOT   403448576ull   // fp32 [256][256] w_out^T
// CRU packed weights overlay the dead WQT region (built after k_qkv_gemm):
#define OFF_WC    402662144ull   // fp32 [2 groups][352][128]  (gwc||pwc1, k-major)
#define OFF_WC2   403022592ull   // fp32 [64][256]             (pwc2||I, k-major)
// attention out bf16 [B][pix][256] — reuses UL region (dead by then)
#define OFF_ATTN  OFF_UL

__device__ __forceinline__ float b2f(bf16 v){ return __bfloat162float(v); }
__device__ __forceinline__ bf16  f2b(float v){ return __float2bfloat16(v); }

// ---------------- transpose of small weight matrices ----------------
__global__ void k_transpose(const float* __restrict__ in, float* __restrict__ out,
                            int R, int Ccols){
  int idx = blockIdx.x * 256 + threadIdx.x;
  if (idx < R * Ccols){
    int r = idx / Ccols, c = idx % Ccols;
    out[c * R + r] = in[idx];
  }
}

// ---------------- CRU weight packing ----------------
// Wc[g][k][c]  (k<288: gwc 3x3 for group g; k>=288: pwc1), c = in-group out-ch
// Wc2[k][c]    (c<192: pwc2; c>=192: identity row for the copy channels)
__global__ void k_wprep(const float* __restrict__ gwc_w, const float* __restrict__ pwc1,
                        const float* __restrict__ pwc2, float* __restrict__ Wc,
                        float* __restrict__ Wc2)
{
  int idx = blockIdx.x * 256 + threadIdx.x;
  if (idx < 90112){
    int c = idx & 127;
    int gk = idx >> 7;       // g*352 + k
    int g = gk / 352, k = gk - g * 352;
    int ch = g * 128 + c;
    Wc[idx] = (k < 288) ? gwc_w[(size_t)ch * 288 + k] : pwc1[ch * 64 + (k - 288)];
  } else if (idx < 90112 + 16384){
    int j = idx - 90112;
    int k = j >> 8, c = j & 255;
    Wc2[j] = (c < 192) ? pwc2[c * 64 + k] : (k == (c - 192) ? 1.f : 0.f);
  }
}

// ---------------- K1: qkv = x @ w_qkv^T + b (rolled coords) ----------------
// M=131072 pixels, N=768, K=256. 128x128 tile, 256 thr, 8x8/thread.
__global__ __launch_bounds__(256) void k_qkv_gemm(
    const float* __restrict__ x, const float* __restrict__ wT,
    const float* __restrict__ bias, bf16* __restrict__ qkv)
{
  __shared__ float As[16][132];
  __shared__ float Bs[16][132];
  int t = threadIdx.x;
  int tx = t & 15, ty = t >> 4;
  int m0 = blockIdx.x * 128, n0 = blockIdx.y * 128;
  float acc[8][8] = {};
  for (int k0 = 0; k0 < 256; k0 += 16){
    #pragma unroll
    for (int l = 0; l < 8; l++){
      int e = t + l * 256;
      int mm = e & 127, kk = e >> 7;
      int m = m0 + mm;
      int b = m >> 16, ij = m & 65535;
      int i = ij >> 8, j = ij & 255;
      int ir = (i + 4) & 255, jr = (j + 4) & 255;
      As[kk][mm] = x[(((size_t)(b * 256 + k0 + kk)) << 16) + (ir << 8) + jr];
    }
    #pragma unroll
    for (int l = 0; l < 8; l++){
      int e = t + l * 256;
      int nn = e & 127, kk = e >> 7;
      Bs[kk][nn] = wT[(size_t)(k0 + kk) * 768 + n0 + nn];
    }
    __syncthreads();
    #pragma unroll
    for (int kk = 0; kk < 16; kk++){
      float4 a0 = *(const float4*)&As[kk][ty * 4];
      float4 a1 = *(const float4*)&As[kk][64 + ty * 4];
      float4 b0 = *(const float4*)&Bs[kk][tx * 4];
      float4 b1 = *(const float4*)&Bs[kk][64 + tx * 4];
      float av[8] = {a0.x,a0.y,a0.z,a0.w,a1.x,a1.y,a1.z,a1.w};
      float bv[8] = {b0.x,b0.y,b0.z,b0.w,b1.x,b1.y,b1.z,b1.w};
      #pragma unroll
      for (int r = 0; r < 8; r++)
        #pragma unroll
        for (int c = 0; c < 8; c++) acc[r][c] += av[r] * bv[c];
    }
    __syncthreads();
  }
  #pragma unroll
  for (int r = 0; r < 8; r++){
    int mr = (r < 4) ? (ty * 4 + r) : (64 + ty * 4 + r - 4);
    int m = m0 + mr;
    int b = m >> 16, ij = m & 65535;
    #pragma unroll
    for (int c = 0; c < 8; c++){
      int nc = (c < 4) ? (tx * 4 + c) : (64 + tx * 4 + c - 4);
      int n = n0 + nc;
      qkv[(((size_t)(b * 768 + n)) << 16) + ij] = f2b(acc[r][c] + bias[n]);
    }
  }
}

// ---------------- K2a: GroupNorm partial stats over Q slice ----------------
__global__ __launch_bounds__(256) void k_gn_stats(const bf16* __restrict__ qkv,
                                                  float* __restrict__ acc)
{
  int blk = blockIdx.x;            // (b*16+g)*8 + s
  int s = blk & 7, bg = blk >> 3;
  int g = bg & 15, b = bg >> 4;
  int t = threadIdx.x;
  float sum = 0.f, sq = 0.f;
  for (int ch = 0; ch < 16; ch++){
    const bf16* base = qkv + (((size_t)(b * 768 + g * 16 + ch)) << 16) + s * 8192;
    for (int p = t; p < 8192; p += 256){
      float v = b2f(base[p]);
      sum += v; sq += v * v;
    }
  }
  __shared__ float rs[256], rq[256];
  rs[t] = sum; rq[t] = sq; __syncthreads();
  for (int st = 128; st > 0; st >>= 1){
    if (t < st){ rs[t] += rs[t + st]; rq[t] += rq[t + st]; }
    __syncthreads();
  }
  if (t == 0){
    atomicAdd(&acc[bg * 2], rs[0]);
    atomicAdd(&acc[bg * 2 + 1], rq[0]);
  }
}

__global__ __launch_bounds__(256) void k_gn_final(const float* __restrict__ acc,
                                                  const float* __restrict__ gn_w,
                                                  float* __restrict__ fin)
{
  __shared__ float red[256];
  int t = threadIdx.x;
  red[t] = gn_w[t]; __syncthreads();
  for (int st = 128; st > 0; st >>= 1){
    if (t < st) red[t] += red[t + st];
    __syncthreads();
  }
  if (t == 0) fin[64] = 1.0f / red[0];
  if (t < 32){
    const float Ninv = 1.0f / 1048576.0f;
    float mu = acc[t * 2] * Ninv;
    float var = acc[t * 2 + 1] * Ninv - mu * mu;
    fin[t * 2] = mu;
    fin[t * 2 + 1] = 1.0f / sqrtf(var + 1e-5f);
  }
}

// ---------------- K2b: SRU apply in-place on Q slice ----------------
__global__ __launch_bounds__(256) void k_sru(bf16* __restrict__ qkv,
    const float* __restrict__ fin, const float* __restrict__ gn_w,
    const float* __restrict__ gn_b)
{
  int idx = blockIdx.x * 256 + threadIdx.x;     // b(2)*c(128)*pix(65536)
  int pix = idx & 65535;
  int bc = idx >> 16;
  int c = bc & 127, b = bc >> 7;
  size_t i1 = (((size_t)(b * 768 + c)) << 16) + pix;
  size_t i2 = (((size_t)(b * 768 + c + 128)) << 16) + pix;
  float x1 = b2f(qkv[i1]);
  float x2 = b2f(qkv[i2]);
  int g1 = c >> 4, g2 = (c + 128) >> 4;
  float mu1 = fin[(b * 16 + g1) * 2], rs1 = fin[(b * 16 + g1) * 2 + 1];
  float mu2 = fin[(b * 16 + g2) * 2], rs2 = fin[(b * 16 + g2) * 2 + 1];
  float invs = fin[64];
  float w1c = gn_w[c], w2c = gn_w[c + 128];
  float gnx1 = (x1 - mu1) * rs1 * w1c + gn_b[c];
  float gnx2 = (x2 - mu2) * rs2 * w2c + gn_b[c + 128];
  float rw1 = 1.0f / (1.0f + __expf(-gnx1 * (w1c * invs)));
  float rw2 = 1.0f / (1.0f + __expf(-gnx2 * (w2c * invs)));
  float a1 = rw1 > 0.5f ? 1.0f : rw1, a2 = rw1 > 0.5f ? 0.0f : rw1;
  float b1 = rw2 > 0.5f ? 1.0f : rw2, b2v = rw2 > 0.5f ? 0.0f : rw2;
  qkv[i1] = f2b(a1 * x1 + b2v * x2);
  qkv[i2] = f2b(b1 * x2 + a2 * x1);
}

// ---------------- K3a: squeeze 1x1 convs on K slice -> ul ----------------
__global__ __launch_bounds__(256) void k_squeeze(const bf16* __restrict__ qkv,
    const float* __restrict__ sq1, const float* __restrict__ sq2,
    float* __restrict__ ul)
{
  __shared__ float in_s[128][65];
  int p0 = blockIdx.x * 64;
  int b = p0 >> 16, pl0 = p0 & 65535;
  int t = threadIdx.x;
  int pp = t & 63, og = t >> 6;      // og in 0..3, 16 outputs each
  // ---- up half (qkv ch 256..383) ----
  for (int e = t; e < 8192; e += 256){
    int ch = e >> 6, px = e & 63;
    in_s[ch][px] = b2f(qkv[(((size_t)(b * 768 + 256 + ch)) << 16) + pl0 + px]);
  }
  __syncthreads();
  {
    float acc[16] = {};
    for (int i = 0; i < 128; i++){
      float v = in_s[i][pp];
      #pragma unroll
      for (int o = 0; o < 16; o++) acc[o] += sq1[(og * 16 + o) * 128 + i] * v;
    }
    #pragma unroll
    for (int o = 0; o < 16; o++)
      ul[(((size_t)(b * 128 + og * 16 + o)) << 16) + pl0 + pp] = acc[o];
  }
  __syncthreads();
  // ---- low half (qkv ch 384..511) ----
  for (int e = t; e < 8192; e += 256){
    int ch = e >> 6, px = e & 63;
    in_s[ch][px] = b2f(qkv[(((size_t)(b * 768 + 384 + ch)) << 16) + pl0 + px]);
  }
  __syncthreads();
  {
    float acc[16] = {};
    for (int i = 0; i < 128; i++){
      float v = in_s[i][pp];
      #pragma unroll
      for (int o = 0; o < 16; o++) acc[o] += sq2[(og * 16 + o) * 128 + i] * v;
    }
    #pragma unroll
    for (int o = 0; o < 16; o++)
      ul[(((size_t)(b * 128 + 64 + og * 16 + o)) << 16) + pl0 + pp] = acc[o];
  }
}

// ---------------- K3b: CRU as GEMM ----------------
// mode 0: y1 = Wc[g] (352x128) . im2col(up_g) ; tile = 8x16 px, 128 ch (one group)
// mode 1: y2 = Wc2 (64x256)   . low          ; ch-halves via blockIdx.y
__global__ __launch_bounds__(256) void k_cru_gemm(
    const float* __restrict__ ul, const float* __restrict__ Wmat,
    const float* __restrict__ gwc_b, bf16* __restrict__ cru, int mode)
{
  __shared__ float As[16][132];   // [kk][px]
  __shared__ float Bs[16][132];   // [kk][ch]
  int t = threadIdx.x;
  int tx = t & 15, ty = t >> 4;
  int tile = blockIdx.x;          // 0..511 : 32 row-tiles x 16 col-tiles
  int yT = blockIdx.y;            // mode0: group; mode1: ch-half
  int b = blockIdx.z;
  int tr = tile >> 4, tc = tile & 15;
  int ty0 = tr * 8, tx0 = tc * 16;
  int K = (mode == 0) ? 352 : 64;
  const float* W = (mode == 0) ? (Wmat + yT * 352 * 128) : Wmat;
  int wstride = (mode == 0) ? 128 : 256;
  int wcol0 = (mode == 0) ? 0 : yT * 128;
  float acc[8][8] = {};
  for (int k0 = 0; k0 < K; k0 += 16){
    #pragma unroll
    for (int l = 0; l < 8; l++){
      int e = t + l * 256;
      int mm = e & 127, kk = e >> 7;
      int k = k0 + kk;
      int py = mm >> 4, pxx = mm & 15;
      float v;
      if (mode == 0){
        int i, dy, dx;
        if (k < 288){
          i = k / 9; int r9 = k - i * 9; dy = r9 / 3; dx = r9 - dy * 3;
          i += yT * 32;
        } else { i = k - 288; dy = 1; dx = 1; }
        int gy = ty0 + py + dy - 1, gx = tx0 + pxx + dx - 1;
        v = (gy >= 0 && gy < 256 && gx >= 0 && gx < 256)
              ? ul[(((size_t)(b * 128 + i)) << 16) + (gy << 8) + gx] : 0.f;
      } else {
        v = ul[(((size_t)(b * 128 + 64 + k)) << 16) + ((ty0 + py) << 8) + tx0 + pxx];
      }
      As[kk][mm] = v;
    }
    #pragma unroll
    for (int l = 0; l < 8; l++){
      int e = t + l * 256;
      int nn = e & 127, kk = e >> 7;
      Bs[kk][nn] = W[(size_t)(k0 + kk) * wstride + wcol0 + nn];
    }
    __syncthreads();
    #pragma unroll
    for (int kk = 0; kk < 16; kk++){
      float4 a0 = *(const float4*)&As[kk][ty * 4];
      float4 a1 = *(const float4*)&As[kk][64 + ty * 4];
      float4 b0 = *(const float4*)&Bs[kk][tx * 4];
      float4 b1 = *(const float4*)&Bs[kk][64 + tx * 4];
      float av[8] = {a0.x,a0.y,a0.z,a0.w,a1.x,a1.y,a1.z,a1.w};
      float bv[8] = {b0.x,b0.y,b0.z,b0.w,b1.x,b1.y,b1.z,b1.w};
      #pragma unroll
      for (int r = 0; r < 8; r++)
        #pragma unroll
        for (int c = 0; c < 8; c++) acc[r][c] += av[r] * bv[c];
    }
    __syncthreads();
  }
  #pragma unroll
  for (int r = 0; r < 8; r++){
    int mr = (r < 4) ? (ty * 4 + r) : (64 + ty * 4 + r - 4);
    int py = mr >> 4, pxx = mr & 15;
    int gpix = ((ty0 + py) << 8) + tx0 + pxx;
    #pragma unroll
    for (int c = 0; c < 8; c++){
      int nc = (c < 4) ? (tx * 4 + c) : (64 + tx * 4 + c - 4);
      int ch; float bv;
      if (mode == 0){ ch = yT * 128 + nc; bv = gwc_b[ch]; }
      else          { ch = 256 + yT * 128 + nc; bv = 0.f; }
      cru[(((size_t)(b * 512 + ch)) << 16) + gpix] = f2b(acc[r][c] + bv);
    }
  }
}

// ---------------- K3d: per-channel sums of cru (for pooled softmax) --------
__global__ __launch_bounds__(256) void k_pool(const bf16* __restrict__ cru,
                                              float* __restrict__ pool)
{
  int bc = blockIdx.x;  // b*512+ch
  const ushort4* p4 = (const ushort4*)(cru + (((size_t)bc) << 16));
  int t = threadIdx.x;
  float s = 0.f;
  for (int i = t; i < 16384; i += 256){
    ushort4 u = p4[i];
    s += b2f(*(bf16*)&u.x) + b2f(*(bf16*)&u.y) + b2f(*(bf16*)&u.z) + b2f(*(bf16*)&u.w);
  }
  __shared__ float red[256];
  red[t] = s; __syncthreads();
  for (int st = 128; st > 0; st >>= 1){
    if (t < st) red[t] += red[t + st];
    __syncthreads();
  }
  if (t == 0) pool[bc] = red[0];
}

// ---------------- K3f: channel softmax of pooled means ----------------
__global__ __launch_bounds__(512) void k_pool_softmax(const float* __restrict__ pool,
                                                      float* __restrict__ s)
{
  __shared__ float red[512];
  int t = threadIdx.x;
  for (int b = 0; b < 2; b++){
    float v = pool[b * 512 + t] * (1.0f / 65536.0f);
    red[t] = v; __syncthreads();
    for (int st = 256; st > 0; st >>= 1){
      if (t < st) red[t] = fmaxf(red[t], red[t + st]);
      __syncthreads();
    }
    float m = red[0]; __syncthreads();
    float e = __expf(v - m);
    red[t] = e; __syncthreads();
    for (int st = 256; st > 0; st >>= 1){
      if (t < st) red[t] += red[t + st];
      __syncthreads();
    }
    float inv = 1.0f / red[0];
    __syncthreads();
    s[b * 512 + t] = e * inv;
  }
}

// ---------------- K3c: k = s1*out1 + s2*out2 -> K slice of qkv ----------------
__global__ __launch_bounds__(256) void k_cru_apply(const bf16* __restrict__ cru,
    const float* __restrict__ s, bf16* __restrict__ qkv)
{
  int idx = blockIdx.x * 256 + threadIdx.x;  // b*256ch*65536pix
  int pix = idx & 65535;
  int bc = idx >> 16;
  int c = bc & 255, b = bc >> 8;
  float v1 = b2f(cru[(((size_t)(b * 512 + c)) << 16) + pix]);
  float v2 = b2f(cru[(((size_t)(b * 512 + 256 + c)) << 16) + pix]);
  float kv = s[b * 512 + c] * v1 + s[b * 512 + 256 + c] * v2;
  qkv[(((size_t)(b * 768 + 256 + c)) << 16) + pix] = f2b(kv);
}

// ---------------- K4: windowed attention ----------------
__global__ __launch_bounds__(64) void k_attn(const bf16* __restrict__ qkv,
    const float* __restrict__ rel_pos, bf16* __restrict__ attn)
{
  __shared__ float k_s[64][33];
  __shared__ float v_s[64][33];
  __shared__ float bias_s[225];
  int win = blockIdx.x, head = blockIdx.y, b = blockIdx.z;
  int hw = win >> 5, wwi = win & 31;
  int t = threadIdx.x;
  for (int e = t; e < 225; e += 64) bias_s[e] = rel_pos[head * 225 + e];
  int pi = t >> 3, pj = t & 7;
  int pix = ((hw * 8 + pi) << 8) | (wwi * 8 + pj);
  size_t base = ((size_t)(b * 768)) << 16;
  float q[32];
  #pragma unroll
  for (int d = 0; d < 32; d++){
    q[d]      = b2f(qkv[base + (((size_t)(      head * 32 + d)) << 16) + pix]);
    k_s[t][d] = b2f(qkv[base + (((size_t)(256 + head * 32 + d)) << 16) + pix]);
    v_s[t][d] = b2f(qkv[base + (((size_t)(512 + head * 32 + d)) << 16) + pix]);
  }
  __syncthreads();
  bool mH = (hw == 31), mW = (wwi == 31);
  float sim[64];
  float mx = -1e30f;
  #pragma unroll
  for (int j = 0; j < 64; j++){
    float sv = 0.f;
    #pragma unroll
    for (int d = 0; d < 32; d++) sv += q[d] * k_s[j][d];
    int ji = j >> 3, jj = j & 7;
    sv = sv * SCALE + bias_s[(pi - ji + 7) * 15 + (pj - jj + 7)];
    bool masked = (mH && ((pi < 4) != (ji < 4))) || (mW && ((pj < 4) != (jj < 4)));
    sv = masked ? -1e30f : sv;
    sim[j] = sv;
    mx = fmaxf(mx, sv);
  }
  float sum = 0.f;
  #pragma unroll
  for (int j = 0; j < 64; j++){
    float e = __expf(sim[j] - mx);
    sim[j] = e; sum += e;
  }
  float inv = 1.0f / sum;
  float o[32] = {};
  #pragma unroll
  for (int j = 0; j < 64; j++){
    float p = sim[j] * inv;
    #pragma unroll
    for (int d = 0; d < 32; d++) o[d] += p * v_s[j][d];
  }
  size_t ob = (((size_t)(b * 65536 + pix)) << 8) + head * 32;
  #pragma unroll
  for (int d = 0; d < 32; d++) attn[ob + d] = f2b(o[d]);
}

// ---------------- K6: out = attn @ w_out^T + b_out, roll back ----------------
__global__ __launch_bounds__(256) void k_proj(const bf16* __restrict__ attn,
    const float* __restrict__ wT, const float* __restrict__ bias,
    float* __restrict__ out)
{
  __shared__ float As[16][132];
  __shared__ float Bs[16][132];
  int t = threadIdx.x;
  int tx = t & 15, ty = t >> 4;
  int m0 = blockIdx.x * 128, n0 = blockIdx.y * 128;
  float acc[8][8] = {};
  for (int k0 = 0; k0 < 256; k0 += 16){
    #pragma unroll
    for (int l = 0; l < 8; l++){
      int e = t + l * 256;
      int mm = e >> 4, kk = e & 15;
      int m = m0 + mm;
      int b = m >> 16, ij = m & 65535;
      int i = ij >> 8, j = ij & 255;
      int ir = (i - 4) & 255, jr = (j - 4) & 255;
      As[kk][mm] = b2f(attn[(((size_t)(b * 65536) + (ir << 8) + jr) << 8) + k0 + kk]);
    }
    #pragma unroll
    for (int l = 0; l < 8; l++){
      int e = t + l * 256;
      int nn = e & 127, kk = e >> 7;
      Bs[kk][nn] = wT[(size_t)(k0 + kk) * 256 + n0 + nn];
    }
    __syncthreads();
    #pragma unroll
    for (int kk = 0; kk < 16; kk++){
      float4 a0 = *(const float4*)&As[kk][ty * 4];
      float4 a1 = *(const float4*)&As[kk][64 + ty * 4];
      float4 b0 = *(const float4*)&Bs[kk][tx * 4];
      float4 b1 = *(const float4*)&Bs[kk][64 + tx * 4];
      float av[8] = {a0.x,a0.y,a0.z,a0.w,a1.x,a1.y,a1.z,a1.w};
      float bv[8] = {b0.x,b0.y,b0.z,b0.w,b1.x,b1.y,b1.z,b1.w};
      #pragma unroll
      for (int r = 0; r < 8; r++)
        #pragma unroll
        for (int c = 0; c < 8; c++) acc[r][c] += av[r] * bv[c];
    }
    __syncthreads();
  }
  #pragma unroll
  for (int r = 0; r < 8; r++){
    int mr = (r < 4) ? (ty * 4 + r) : (64 + ty * 4 + r - 4);
    int m = m0 + mr;
    int b = m >> 16, ij = m & 65535;
    #pragma unroll
    for (int c = 0; c < 8; c++){
      int nc = (c < 4) ? (tx * 4 + c) : (64 + tx * 4 + c - 4);
      int n = n0 + nc;
      out[(((size_t)(b * 256 + n)) << 16) + ij] = acc[r][c] + bias[n];
    }
  }
}

extern "C" void kernel_launch(void* const* d_in, const int* in_sizes, int n_in,
                              void* d_out, int out_size, void* d_ws, size_t ws_size,
                              hipStream_t stream) {
  const float* x       = (const float*)d_in[0];
  const float* w_qkv   = (const float*)d_in[1];
  const float* b_qkv   = (const float*)d_in[2];
  const float* rel_pos = (const float*)d_in[3];
  const float* gn_w    = (const float*)d_in[4];
  const float* gn_b    = (const float*)d_in[5];
  const float* sq1     = (const float*)d_in[6];
  const float* sq2     = (const float*)d_in[7];
  const float* gwc_w   = (const float*)d_in[8];
  const float* gwc_b   = (const float*)d_in[9];
  const float* pwc1    = (const float*)d_in[10];
  const float* pwc2    = (const float*)d_in[11];
  const float* w_out   = (const float*)d_in[12];
  const float* b_out   = (const float*)d_in[13];
  float* out = (float*)d_out;

  char* ws = (char*)d_ws;
  bf16*  qkv   = (bf16*)(ws + OFF_QKV);
  float* ul    = (float*)(ws + OFF_UL);
  bf16*  cru   = (bf16*)(ws + OFF_CRU);
  float* pool  = (float*)(ws + OFF_POOL);
  float* gnacc = (float*)(ws + OFF_GNACC);
  float* gnfin = (float*)(ws + OFF_GNFIN);
  float* smax  = (float*)(ws + OFF_SOFT);
  float* wqkvT = (float*)(ws + OFF_WQT);
  float* woutT = (float*)(ws + OFF_WOT);
  float* Wc    = (float*)(ws + OFF_WC);
  float* Wc2   = (float*)(ws + OFF_WC2);
  bf16*  attn  = (bf16*)(ws + OFF_ATTN);

  hipMemsetAsync(ws + OFF_GNACC, 0, 256, stream);
  k_transpose<<<768, 256, 0, stream>>>(w_qkv, wqkvT, 768, 256);
  k_transpose<<<256, 256, 0, stream>>>(w_out, woutT, 256, 256);
  k_qkv_gemm<<<dim3(1024, 6), 256, 0, stream>>>(x, wqkvT, b_qkv, qkv);
  // Wc overwrites wqkvT (dead after k_qkv_gemm); stream order guarantees safety
  k_wprep<<<416, 256, 0, stream>>>(gwc_w, pwc1, pwc2, Wc, Wc2);
  k_gn_stats<<<256, 256, 0, stream>>>(qkv, gnacc);
  k_gn_final<<<1, 256, 0, stream>>>(gnacc, gn_w, gnfin);
  k_sru<<<65536, 256, 0, stream>>>(qkv, gnfin, gn_w, gn_b);
  k_squeeze<<<2048, 256, 0, stream>>>(qkv, sq1, sq2, ul);
  k_cru_gemm<<<dim3(512, 2, 2), 256, 0, stream>>>(ul, Wc, gwc_b, cru, 0);
  k_cru_gemm<<<dim3(512, 2, 2), 256, 0, stream>>>(ul, Wc2, gwc_b, cru, 1);
  k_pool<<<1024, 256, 0, stream>>>(cru, pool);
  k_pool_softmax<<<1, 512, 0, stream>>>(pool, smax);
  k_cru_apply<<<131072, 256, 0, stream>>>(cru, smax, qkv);
  k_attn<<<dim3(1024, 8, 2), 64, 0, stream>>>(qkv, rel_pos, attn);
  k_proj<<<dim3(1024, 2), 256, 0, stream>>>(attn, woutT, b_out, out);
}

// Round 3
// 2528.874 us; speedup vs baseline: 2.4521x; 1.1917x over previous
//
#include <hip/hip_runtime.h>
#include <hip/hip_bf16.h>

typedef __hip_bfloat16 bf16;
typedef __attribute__((ext_vector_type(8))) short s16x8;
typedef __attribute__((ext_vector_type(4))) float f32x4;

#define SCALE 0.17677669529663687f

// ---- workspace offsets (bytes) ----
#define OFF_QKV   0ull            // bf16 [B][768][256][256] (rolled coords)
#define OFF_UL    201326592ull    // fp32 [B][128][256][256] squeeze out; later attn_sw bf16
#define OFF_CRU   268435456ull    // bf16 [B][512][256][256] cru pre-softmax
#define OFF_XT    OFF_CRU         // bf16 [131072][256] swizzled xT (dead before cru written)
#define OFF_POOL  402653184ull    // fp32 [2][512]
#define OFF_GNACC 402657280ull    // fp32 [2][16][2]
#define OFF_GNFIN 402657536ull    // fp32 mu/rstd + [64]=1/sum(gn_w)
#define OFF_SOFT  402658048ull    // fp32 [2][512]
#define OFF_WC    402662144ull    // fp32 [2][352][128]
#define OFF_WC2   403022592ull    // fp32 [64][256]
#define OFF_WQS   403088128ull    // bf16 [768][256] swizzled
#define OFF_WOS   403481344ull    // bf16 [256][256] swizzled
#define OFF_ATTN  OFF_UL          // bf16 [131072][256] swizzled attn out (final pix order)

__device__ __forceinline__ float b2f(bf16 v){ return __bfloat162float(v); }
__device__ __forceinline__ bf16  f2b(float v){ return __float2bfloat16(v); }
__device__ __forceinline__ ushort f2bu(float v){ bf16 b = __float2bfloat16(v); return *(ushort*)&b; }
__device__ __forceinline__ uint pk2(float a, float b){ return (uint)f2bu(a) | ((uint)f2bu(b) << 16); }

__device__ __forceinline__ void gload16(const void* g, void* l){
  __builtin_amdgcn_global_load_lds((const __attribute__((address_space(1))) unsigned int*)g,
                                   (__attribute__((address_space(3))) unsigned int*)l, 16, 0, 0);
}

// ---------------- weight prep: CRU pack + bf16-swizzled wq/wo ----------------
__global__ void k_wprep(const float* __restrict__ gwc_w, const float* __restrict__ pwc1,
                        const float* __restrict__ pwc2, const float* __restrict__ w_qkv,
                        const float* __restrict__ w_out, float* __restrict__ Wc,
                        float* __restrict__ Wc2, char* __restrict__ wqs, char* __restrict__ wos)
{
  int idx = blockIdx.x * 256 + threadIdx.x;
  if (idx < 90112){
    int c = idx & 127;
    int gk = idx >> 7;       // g*352 + k
    int g = gk / 352, k = gk - g * 352;
    int ch = g * 128 + c;
    Wc[idx] = (k < 288) ? gwc_w[(size_t)ch * 288 + k] : pwc1[ch * 64 + (k - 288)];
  } else if (idx < 106496){
    int j = idx - 90112;
    int k = j >> 8, c = j & 255;
    Wc2[j] = (c < 192) ? pwc2[c * 64 + k] : (k == (c - 192) ? 1.f : 0.f);
  } else if (idx < 303104){
    int j = idx - 106496;
    int n = j >> 8, k = j & 255;
    *(ushort*)(wqs + (size_t)n * 512 + ((k * 2) ^ ((n & 7) << 4))) = f2bu(w_qkv[n * 256 + k]);
  } else if (idx < 368640){
    int j = idx - 303104;
    int n = j >> 8, k = j & 255;
    *(ushort*)(wos + (size_t)n * 512 + ((k * 2) ^ ((n & 7) << 4))) = f2bu(w_out[n * 256 + k]);
  }
}

// ---------------- xT: x fp32 [ch][pix] -> bf16 [rolled pix][ch], XOR-swizzled ----
__global__ __launch_bounds__(256) void k_xt(const float* __restrict__ x, char* __restrict__ xt)
{
  __shared__ ushort Ls[64][66];
  int t = threadIdx.x;
  int jt = blockIdx.x;        // 0..3 (64-wide j tile)
  int i  = blockIdx.y;        // 0..255
  int zc = blockIdx.z;        // b*4 + ch-tile
  int ct = zc & 3, b = zc >> 2;
  int ch0 = ct * 64, j0 = jt * 64;
  for (int e = t; e < 4096; e += 256){
    int ch = e >> 6, jj = e & 63;
    Ls[ch][jj] = f2bu(x[(((size_t)(b * 256 + ch0 + ch)) << 16) + (i << 8) + j0 + jj]);
  }
  __syncthreads();
  int ri = (i - 4) & 255;
  #pragma unroll
  for (int s = 0; s < 2; s++){
    int id = s * 256 + t;
    int jj = id >> 3, blk = id & 7;
    int rj = (j0 + jj - 4) & 255;
    int m = (b << 16) + (ri << 8) + rj;
    ushort u0 = Ls[blk*8+0][jj], u1 = Ls[blk*8+1][jj], u2 = Ls[blk*8+2][jj], u3 = Ls[blk*8+3][jj];
    ushort u4 = Ls[blk*8+4][jj], u5 = Ls[blk*8+5][jj], u6 = Ls[blk*8+6][jj], u7 = Ls[blk*8+7][jj];
    uint4 pkv;
    pkv.x = (uint)u0 | ((uint)u1 << 16);
    pkv.y = (uint)u2 | ((uint)u3 << 16);
    pkv.z = (uint)u4 | ((uint)u5 << 16);
    pkv.w = (uint)u6 | ((uint)u7 << 16);
    size_t byte = (size_t)m * 512 + (((ch0 + blk * 8) * 2) ^ ((m & 7) << 4));
    *(uint4*)(xt + byte) = pkv;
  }
}

// ---------------- K1: qkv = xT @ wq^T + b via MFMA bf16 ----------------
// M=131072, N=768, K=256. 128x128 tile, BK=64, 4 waves (2x2), 64x64 each.
__global__ __launch_bounds__(256) void k_qkv_mfma(
    const char* __restrict__ xt, const char* __restrict__ wq,
    const float* __restrict__ bias, bf16* __restrict__ qkv)
{
  __shared__ char sm[32768];
  int t = threadIdx.x;
  int l = t & 63, w = t >> 6;
  int ln = l & 15, l4 = l >> 4;
  int m0 = blockIdx.x * 128, n0 = blockIdx.y * 128;
  int wm0 = (w >> 1) * 64, wn0 = (w & 1) * 64;
  f32x4 acc[4][4];
  #pragma unroll
  for (int a = 0; a < 4; a++)
    #pragma unroll
    for (int c = 0; c < 4; c++) acc[a][c] = (f32x4){0.f, 0.f, 0.f, 0.f};
  const char* gA = xt + (size_t)(m0 + w * 32 + (l >> 3)) * 512 + (l & 7) * 16;
  const char* gB = wq + (size_t)(n0 + w * 32 + (l >> 3)) * 512 + (l & 7) * 16;
  char* ldsA = sm + (w * 32) * 128;
  char* ldsB = sm + 16384 + (w * 32) * 128;
  for (int k0 = 0; k0 < 256; k0 += 64){
    #pragma unroll
    for (int c = 0; c < 4; c++){
      gload16(gA + (size_t)k0 * 2 + c * 4096, ldsA + c * 1024);
      gload16(gB + (size_t)k0 * 2 + c * 4096, ldsB + c * 1024);
    }
    __syncthreads();
    s16x8 af[4][2], bfr[4][2];
    #pragma unroll
    for (int mi = 0; mi < 4; mi++){
      int r = wm0 + mi * 16 + ln;
      int key = (r & 7) << 4;
      #pragma unroll
      for (int kk = 0; kk < 2; kk++)
        af[mi][kk] = *(const s16x8*)(sm + r * 128 + ((kk * 64 + l4 * 16) ^ key));
    }
    #pragma unroll
    for (int ni = 0; ni < 4; ni++){
      int r = wn0 + ni * 16 + ln;
      int key = (r & 7) << 4;
      #pragma unroll
      for (int kk = 0; kk < 2; kk++)
        bfr[ni][kk] = *(const s16x8*)(sm + 16384 + r * 128 + ((kk * 64 + l4 * 16) ^ key));
    }
    #pragma unroll
    for (int kk = 0; kk < 2; kk++)
      #pragma unroll
      for (int mi = 0; mi < 4; mi++)
        #pragma unroll
        for (int ni = 0; ni < 4; ni++)
          acc[mi][ni] = __builtin_amdgcn_mfma_f32_16x16x32_bf16(af[mi][kk], bfr[ni][kk], acc[mi][ni], 0, 0, 0);
    __syncthreads();
  }
  #pragma unroll
  for (int ni = 0; ni < 4; ni++){
    int n = n0 + wn0 + ni * 16 + ln;
    float bs = bias[n];
    #pragma unroll
    for (int mi = 0; mi < 4; mi++){
      int mb = m0 + wm0 + mi * 16 + l4 * 4;
      int b = mb >> 16, pix = mb & 65535;
      ushort4 pkv;
      pkv.x = f2bu(acc[mi][ni].x + bs);
      pkv.y = f2bu(acc[mi][ni].y + bs);
      pkv.z = f2bu(acc[mi][ni].z + bs);
      pkv.w = f2bu(acc[mi][ni].w + bs);
      *(ushort4*)((char*)qkv + (((size_t)(b * 768 + n)) << 17) + pix * 2) = pkv;
    }
  }
}

// ---------------- K2a: GroupNorm partial stats over Q slice ----------------
__global__ __launch_bounds__(256) void k_gn_stats(const bf16* __restrict__ qkv,
                                                  float* __restrict__ acc)
{
  int blk = blockIdx.x;            // (b*16+g)*8 + s
  int s = blk & 7, bg = blk >> 3;
  int g = bg & 15, b = bg >> 4;
  int t = threadIdx.x;
  float sum = 0.f, sq = 0.f;
  for (int ch = 0; ch < 16; ch++){
    const bf16* base = qkv + (((size_t)(b * 768 + g * 16 + ch)) << 16) + s * 8192;
    for (int p = t; p < 8192; p += 256){
      float v = b2f(base[p]);
      sum += v; sq += v * v;
    }
  }
  __shared__ float rs[256], rq[256];
  rs[t] = sum; rq[t] = sq; __syncthreads();
  for (int st = 128; st > 0; st >>= 1){
    if (t < st){ rs[t] += rs[t + st]; rq[t] += rq[t + st]; }
    __syncthreads();
  }
  if (t == 0){
    atomicAdd(&acc[bg * 2], rs[0]);
    atomicAdd(&acc[bg * 2 + 1], rq[0]);
  }
}

__global__ __launch_bounds__(256) void k_gn_final(const float* __restrict__ acc,
                                                  const float* __restrict__ gn_w,
                                                  float* __restrict__ fin)
{
  __shared__ float red[256];
  int t = threadIdx.x;
  red[t] = gn_w[t]; __syncthreads();
  for (int st = 128; st > 0; st >>= 1){
    if (t < st) red[t] += red[t + st];
    __syncthreads();
  }
  if (t == 0) fin[64] = 1.0f / red[0];
  if (t < 32){
    const float Ninv = 1.0f / 1048576.0f;
    float mu = acc[t * 2] * Ninv;
    float var = acc[t * 2 + 1] * Ninv - mu * mu;
    fin[t * 2] = mu;
    fin[t * 2 + 1] = 1.0f / sqrtf(var + 1e-5f);
  }
}

// ---------------- K2b: SRU apply in-place on Q slice ----------------
__global__ __launch_bounds__(256) void k_sru(bf16* __restrict__ qkv,
    const float* __restrict__ fin, const float* __restrict__ gn_w,
    const float* __restrict__ gn_b)
{
  int idx = blockIdx.x * 256 + threadIdx.x;     // b(2)*c(128)*pix(65536)
  int pix = idx & 65535;
  int bc = idx >> 16;
  int c = bc & 127, b = bc >> 7;
  size_t i1 = (((size_t)(b * 768 + c)) << 16) + pix;
  size_t i2 = (((size_t)(b * 768 + c + 128)) << 16) + pix;
  float x1 = b2f(qkv[i1]);
  float x2 = b2f(qkv[i2]);
  int g1 = c >> 4, g2 = (c + 128) >> 4;
  float mu1 = fin[(b * 16 + g1) * 2], rs1 = fin[(b * 16 + g1) * 2 + 1];
  float mu2 = fin[(b * 16 + g2) * 2], rs2 = fin[(b * 16 + g2) * 2 + 1];
  float invs = fin[64];
  float w1c = gn_w[c], w2c = gn_w[c + 128];
  float gnx1 = (x1 - mu1) * rs1 * w1c + gn_b[c];
  float gnx2 = (x2 - mu2) * rs2 * w2c + gn_b[c + 128];
  float rw1 = 1.0f / (1.0f + __expf(-gnx1 * (w1c * invs)));
  float rw2 = 1.0f / (1.0f + __expf(-gnx2 * (w2c * invs)));
  float a1 = rw1 > 0.5f ? 1.0f : rw1, a2 = rw1 > 0.5f ? 0.0f : rw1;
  float b1 = rw2 > 0.5f ? 1.0f : rw2, b2v = rw2 > 0.5f ? 0.0f : rw2;
  qkv[i1] = f2b(a1 * x1 + b2v * x2);
  qkv[i2] = f2b(b1 * x2 + a2 * x1);
}

// ---------------- K3a: squeeze 1x1 convs on K slice -> ul ----------------
__global__ __launch_bounds__(256) void k_squeeze(const bf16* __restrict__ qkv,
    const float* __restrict__ sq1, const float* __restrict__ sq2,
    float* __restrict__ ul)
{
  __shared__ float in_s[128][65];
  int p0 = blockIdx.x * 64;
  int b = p0 >> 16, pl0 = p0 & 65535;
  int t = threadIdx.x;
  int pp = t & 63, og = t >> 6;      // og in 0..3, 16 outputs each
  for (int e = t; e < 8192; e += 256){
    int ch = e >> 6, px = e & 63;
    in_s[ch][px] = b2f(qkv[(((size_t)(b * 768 + 256 + ch)) << 16) + pl0 + px]);
  }
  __syncthreads();
  {
    float acc[16] = {};
    for (int i = 0; i < 128; i++){
      float v = in_s[i][pp];
      #pragma unroll
      for (int o = 0; o < 16; o++) acc[o] += sq1[(og * 16 + o) * 128 + i] * v;
    }
    #pragma unroll
    for (int o = 0; o < 16; o++)
      ul[(((size_t)(b * 128 + og * 16 + o)) << 16) + pl0 + pp] = acc[o];
  }
  __syncthreads();
  for (int e = t; e < 8192; e += 256){
    int ch = e >> 6, px = e & 63;
    in_s[ch][px] = b2f(qkv[(((size_t)(b * 768 + 384 + ch)) << 16) + pl0 + px]);
  }
  __syncthreads();
  {
    float acc[16] = {};
    for (int i = 0; i < 128; i++){
      float v = in_s[i][pp];
      #pragma unroll
      for (int o = 0; o < 16; o++) acc[o] += sq2[(og * 16 + o) * 128 + i] * v;
    }
    #pragma unroll
    for (int o = 0; o < 16; o++)
      ul[(((size_t)(b * 128 + 64 + og * 16 + o)) << 16) + pl0 + pp] = acc[o];
  }
}

// ---------------- K3b: CRU as GEMM (fp32) ----------------
__global__ __launch_bounds__(256) void k_cru_gemm(
    const float* __restrict__ ul, const float* __restrict__ Wmat,
    const float* __restrict__ gwc_b, bf16* __restrict__ cru, int mode)
{
  __shared__ float As[16][132];   // [kk][px]
  __shared__ float Bs[16][132];   // [kk][ch]
  int t = threadIdx.x;
  int tx = t & 15, ty = t >> 4;
  int tile = blockIdx.x;          // 32 row-tiles x 16 col-tiles
  int yT = blockIdx.y;
  int b = blockIdx.z;
  int tr = tile >> 4, tc = tile & 15;
  int ty0 = tr * 8, tx0 = tc * 16;
  int K = (mode == 0) ? 352 : 64;
  const float* W = (mode == 0) ? (Wmat + yT * 352 * 128) : Wmat;
  int wstride = (mode == 0) ? 128 : 256;
  int wcol0 = (mode == 0) ? 0 : yT * 128;
  float acc[8][8] = {};
  for (int k0 = 0; k0 < K; k0 += 16){
    #pragma unroll
    for (int l = 0; l < 8; l++){
      int e = t + l * 256;
      int mm = e & 127, kk = e >> 7;
      int k = k0 + kk;
      int py = mm >> 4, pxx = mm & 15;
      float v;
      if (mode == 0){
        int i, dy, dx;
        if (k < 288){
          i = k / 9; int r9 = k - i * 9; dy = r9 / 3; dx = r9 - dy * 3;
          i += yT * 32;
        } else { i = k - 288; dy = 1; dx = 1; }
        int gy = ty0 + py + dy - 1, gx = tx0 + pxx + dx - 1;
        v = (gy >= 0 && gy < 256 && gx >= 0 && gx < 256)
              ? ul[(((size_t)(b * 128 + i)) << 16) + (gy << 8) + gx] : 0.f;
      } else {
        v = ul[(((size_t)(b * 128 + 64 + k)) << 16) + ((ty0 + py) << 8) + tx0 + pxx];
      }
      As[kk][mm] = v;
    }
    #pragma unroll
    for (int l = 0; l < 8; l++){
      int e = t + l * 256;
      int nn = e & 127, kk = e >> 7;
      Bs[kk][nn] = W[(size_t)(k0 + kk) * wstride + wcol0 + nn];
    }
    __syncthreads();
    #pragma unroll
    for (int kk = 0; kk < 16; kk++){
      float4 a0 = *(const float4*)&As[kk][ty * 4];
      float4 a1 = *(const float4*)&As[kk][64 + ty * 4];
      float4 b0 = *(const float4*)&Bs[kk][tx * 4];
      float4 b1 = *(const float4*)&Bs[kk][64 + tx * 4];
      float av[8] = {a0.x,a0.y,a0.z,a0.w,a1.x,a1.y,a1.z,a1.w};
      float bv[8] = {b0.x,b0.y,b0.z,b0.w,b1.x,b1.y,b1.z,b1.w};
      #pragma unroll
      for (int r = 0; r < 8; r++)
        #pragma unroll
        for (int c = 0; c < 8; c++) acc[r][c] += av[r] * bv[c];
    }
    __syncthreads();
  }
  #pragma unroll
  for (int r = 0; r < 8; r++){
    int mr = (r < 4) ? (ty * 4 + r) : (64 + ty * 4 + r - 4);
    int py = mr >> 4, pxx = mr & 15;
    int gpix = ((ty0 + py) << 8) + tx0 + pxx;
    #pragma unroll
    for (int c = 0; c < 8; c++){
      int nc = (c < 4) ? (tx * 4 + c) : (64 + tx * 4 + c - 4);
      int ch; float bv;
      if (mode == 0){ ch = yT * 128 + nc; bv = gwc_b[ch]; }
      else          { ch = 256 + yT * 128 + nc; bv = 0.f; }
      cru[(((size_t)(b * 512 + ch)) << 16) + gpix] = f2b(acc[r][c] + bv);
    }
  }
}

// ---------------- K3d: per-channel sums of cru ----------------
__global__ __launch_bounds__(256) void k_pool(const bf16* __restrict__ cru,
                                              float* __restrict__ pool)
{
  int bc = blockIdx.x;  // b*512+ch
  const ushort4* p4 = (const ushort4*)(cru + (((size_t)bc) << 16));
  int t = threadIdx.x;
  float s = 0.f;
  for (int i = t; i < 16384; i += 256){
    ushort4 u = p4[i];
    s += b2f(*(bf16*)&u.x) + b2f(*(bf16*)&u.y) + b2f(*(bf16*)&u.z) + b2f(*(bf16*)&u.w);
  }
  __shared__ float red[256];
  red[t] = s; __syncthreads();
  for (int st = 128; st > 0; st >>= 1){
    if (t < st) red[t] += red[t + st];
    __syncthreads();
  }
  if (t == 0) pool[bc] = red[0];
}

// ---------------- K3f: channel softmax of pooled means ----------------
__global__ __launch_bounds__(512) void k_pool_softmax(const float* __restrict__ pool,
                                                      float* __restrict__ s)
{
  __shared__ float red[512];
  int t = threadIdx.x;
  for (int b = 0; b < 2; b++){
    float v = pool[b * 512 + t] * (1.0f / 65536.0f);
    red[t] = v; __syncthreads();
    for (int st = 256; st > 0; st >>= 1){
      if (t < st) red[t] = fmaxf(red[t], red[t + st]);
      __syncthreads();
    }
    float m = red[0]; __syncthreads();
    float e = __expf(v - m);
    red[t] = e; __syncthreads();
    for (int st = 256; st > 0; st >>= 1){
      if (t < st) red[t] += red[t + st];
      __syncthreads();
    }
    float inv = 1.0f / red[0];
    __syncthreads();
    s[b * 512 + t] = e * inv;
  }
}

// ---------------- K3c: k = s1*out1 + s2*out2 -> K slice of qkv ----------------
__global__ __launch_bounds__(256) void k_cru_apply(const bf16* __restrict__ cru,
    const float* __restrict__ s, bf16* __restrict__ qkv)
{
  int idx = blockIdx.x * 256 + threadIdx.x;  // b*256ch*65536pix
  int pix = idx & 65535;
  int bc = idx >> 16;
  int c = bc & 255, b = bc >> 8;
  float v1 = b2f(cru[(((size_t)(b * 512 + c)) << 16) + pix]);
  float v2 = b2f(cru[(((size_t)(b * 512 + 256 + c)) << 16) + pix]);
  float kv = s[b * 512 + c] * v1 + s[b * 512 + 256 + c] * v2;
  qkv[(((size_t)(b * 768 + 256 + c)) << 16) + pix] = f2b(kv);
}

// ---------------- K4: windowed attention ----------------
__global__ __launch_bounds__(64) void k_attn(const bf16* __restrict__ qkv,
    const float* __restrict__ rel_pos, char* __restrict__ attnb)
{
  __shared__ float k_s[64][33];
  __shared__ float v_s[64][33];
  __shared__ float bias_s[225];
  int win = blockIdx.x, head = blockIdx.y, b = blockIdx.z;
  int hw = win >> 5, wwi = win & 31;
  int t = threadIdx.x;
  for (int e = t; e < 225; e += 64) bias_s[e] = rel_pos[head * 225 + e];
  int pi = t >> 3, pj = t & 7;
  int pix = ((hw * 8 + pi) << 8) | (wwi * 8 + pj);
  size_t base = ((size_t)(b * 768)) << 16;
  float q[32];
  #pragma unroll
  for (int d = 0; d < 32; d++){
    q[d]      = b2f(qkv[base + (((size_t)(      head * 32 + d)) << 16) + pix]);
    k_s[t][d] = b2f(qkv[base + (((size_t)(256 + head * 32 + d)) << 16) + pix]);
    v_s[t][d] = b2f(qkv[base + (((size_t)(512 + head * 32 + d)) << 16) + pix]);
  }
  __syncthreads();
  bool mH = (hw == 31), mW = (wwi == 31);
  float sim[64];
  float mx = -1e30f;
  #pragma unroll
  for (int j = 0; j < 64; j++){
    float sv = 0.f;
    #pragma unroll
    for (int d = 0; d < 32; d++) sv += q[d] * k_s[j][d];
    int ji = j >> 3, jj = j & 7;
    sv = sv * SCALE + bias_s[(pi - ji + 7) * 15 + (pj - jj + 7)];
    bool masked = (mH && ((pi < 4) != (ji < 4))) || (mW && ((pj < 4) != (jj < 4)));
    sv = masked ? -1e30f : sv;
    sim[j] = sv;
    mx = fmaxf(mx, sv);
  }
  float sum = 0.f;
  #pragma unroll
  for (int j = 0; j < 64; j++){
    float e = __expf(sim[j] - mx);
    sim[j] = e; sum += e;
  }
  float inv = 1.0f / sum;
  float o[32] = {};
  #pragma unroll
  for (int j = 0; j < 64; j++){
    float p = sim[j] * inv;
    #pragma unroll
    for (int d = 0; d < 32; d++) o[d] += p * v_s[j][d];
  }
  // write at rolled-back pixel, XOR-swizzled row for MFMA proj staging
  int ii = hw * 8 + pi, jjp = wwi * 8 + pj;
  int om = (b << 16) + (((ii + 4) & 255) << 8) + ((jjp + 4) & 255);
  size_t rb = (size_t)om * 512;
  int key = (om & 7) << 4;
  #pragma unroll
  for (int d0 = 0; d0 < 32; d0 += 8){
    uint4 pkv;
    pkv.x = pk2(o[d0+0], o[d0+1]);
    pkv.y = pk2(o[d0+2], o[d0+3]);
    pkv.z = pk2(o[d0+4], o[d0+5]);
    pkv.w = pk2(o[d0+6], o[d0+7]);
    *(uint4*)(attnb + rb + ((head * 64 + d0 * 2) ^ key)) = pkv;
  }
}

// ---------------- K6: out = attn @ w_out^T + b_out via MFMA ----------------
__global__ __launch_bounds__(256) void k_proj_mfma(
    const char* __restrict__ at, const char* __restrict__ wo,
    const float* __restrict__ bias, float* __restrict__ outp)
{
  __shared__ char sm[32768];
  int t = threadIdx.x;
  int l = t & 63, w = t >> 6;
  int ln = l & 15, l4 = l >> 4;
  int m0 = blockIdx.x * 128, n0 = blockIdx.y * 128;
  int wm0 = (w >> 1) * 64, wn0 = (w & 1) * 64;
  f32x4 acc[4][4];
  #pragma unroll
  for (int a = 0; a < 4; a++)
    #pragma unroll
    for (int c = 0; c < 4; c++) acc[a][c] = (f32x4){0.f, 0.f, 0.f, 0.f};
  const char* gA = at + (size_t)(m0 + w * 32 + (l >> 3)) * 512 + (l & 7) * 16;
  const char* gB = wo + (size_t)(n0 + w * 32 + (l >> 3)) * 512 + (l & 7) * 16;
  char* ldsA = sm + (w * 32) * 128;
  char* ldsB = sm + 16384 + (w * 32) * 128;
  for (int k0 = 0; k0 < 256; k0 += 64){
    #pragma unroll
    for (int c = 0; c < 4; c++){
      gload16(gA + (size_t)k0 * 2 + c * 4096, ldsA + c * 1024);
      gload16(gB + (size_t)k0 * 2 + c * 4096, ldsB + c * 1024);
    }
    __syncthreads();
    s16x8 af[4][2], bfr[4][2];
    #pragma unroll
    for (int mi = 0; mi < 4; mi++){
      int r = wm0 + mi * 16 + ln;
      int key = (r & 7) << 4;
      #pragma unroll
      for (int kk = 0; kk < 2; kk++)
        af[mi][kk] = *(const s16x8*)(sm + r * 128 + ((kk * 64 + l4 * 16) ^ key));
    }
    #pragma unroll
    for (int ni = 0; ni < 4; ni++){
      int r = wn0 + ni * 16 + ln;
      int key = (r & 7) << 4;
      #pragma unroll
      for (int kk = 0; kk < 2; kk++)
        bfr[ni][kk] = *(const s16x8*)(sm + 16384 + r * 128 + ((kk * 64 + l4 * 16) ^ key));
    }
    #pragma unroll
    for (int kk = 0; kk < 2; kk++)
      #pragma unroll
      for (int mi = 0; mi < 4; mi++)
        #pragma unroll
        for (int ni = 0; ni < 4; ni++)
          acc[mi][ni] = __builtin_amdgcn_mfma_f32_16x16x32_bf16(af[mi][kk], bfr[ni][kk], acc[mi][ni], 0, 0, 0);
    __syncthreads();
  }
  #pragma unroll
  for (int ni = 0; ni < 4; ni++){
    int n = n0 + wn0 + ni * 16 + ln;
    float bs = bias[n];
    #pragma unroll
    for (int mi = 0; mi < 4; mi++){
      int mb = m0 + wm0 + mi * 16 + l4 * 4;
      int b = mb >> 16, pix = mb & 65535;
      float4 v;
      v.x = acc[mi][ni].x + bs;
      v.y = acc[mi][ni].y + bs;
      v.z = acc[mi][ni].z + bs;
      v.w = acc[mi][ni].w + bs;
      *(float4*)(outp + (((size_t)(b * 256 + n)) << 16) + pix) = v;
    }
  }
}

extern "C" void kernel_launch(void* const* d_in, const int* in_sizes, int n_in,
                              void* d_out, int out_size, void* d_ws, size_t ws_size,
                              hipStream_t stream) {
  const float* x       = (const float*)d_in[0];
  const float* w_qkv   = (const float*)d_in[1];
  const float* b_qkv   = (const float*)d_in[2];
  const float* rel_pos = (const float*)d_in[3];
  const float* gn_w    = (const float*)d_in[4];
  const float* gn_b    = (const float*)d_in[5];
  const float* sq1     = (const float*)d_in[6];
  const float* sq2     = (const float*)d_in[7];
  const float* gwc_w   = (const float*)d_in[8];
  const float* gwc_b   = (const float*)d_in[9];
  const float* pwc1    = (const float*)d_in[10];
  const float* pwc2    = (const float*)d_in[11];
  const float* w_out   = (const float*)d_in[12];
  const float* b_out   = (const float*)d_in[13];
  float* out = (float*)d_out;

  char* ws = (char*)d_ws;
  bf16*  qkv   = (bf16*)(ws + OFF_QKV);
  float* ul    = (float*)(ws + OFF_UL);
  bf16*  cru   = (bf16*)(ws + OFF_CRU);
  char*  xt    = ws + OFF_XT;
  float* pool  = (float*)(ws + OFF_POOL);
  float* gnacc = (float*)(ws + OFF_GNACC);
  float* gnfin = (float*)(ws + OFF_GNFIN);
  float* smax  = (float*)(ws + OFF_SOFT);
  float* Wc    = (float*)(ws + OFF_WC);
  float* Wc2   = (float*)(ws + OFF_WC2);
  char*  wqs   = ws + OFF_WQS;
  char*  wos   = ws + OFF_WOS;
  char*  attnb = ws + OFF_ATTN;

  hipMemsetAsync(ws + OFF_GNACC, 0, 256, stream);
  k_wprep<<<1440, 256, 0, stream>>>(gwc_w, pwc1, pwc2, w_qkv, w_out, Wc, Wc2, wqs, wos);
  k_xt<<<dim3(4, 256, 8), 256, 0, stream>>>(x, xt);
  k_qkv_mfma<<<dim3(1024, 6), 256, 0, stream>>>(xt, wqs, b_qkv, qkv);
  k_gn_stats<<<256, 256, 0, stream>>>(qkv, gnacc);
  k_gn_final<<<1, 256, 0, stream>>>(gnacc, gn_w, gnfin);
  k_sru<<<65536, 256, 0, stream>>>(qkv, gnfin, gn_w, gn_b);
  k_squeeze<<<2048, 256, 0, stream>>>(qkv, sq1, sq2, ul);
  k_cru_gemm<<<dim3(512, 2, 2), 256, 0, stream>>>(ul, Wc, gwc_b, cru, 0);
  k_cru_gemm<<<dim3(512, 2, 2), 256, 0, stream>>>(ul, Wc2, gwc_b, cru, 1);
  k_pool<<<1024, 256, 0, stream>>>(cru, pool);
  k_pool_softmax<<<1, 512, 0, stream>>>(pool, smax);
  k_cru_apply<<<131072, 256, 0, stream>>>(cru, smax, qkv);
  k_attn<<<dim3(1024, 8, 2), 64, 0, stream>>>(qkv, rel_pos, attnb);
  k_proj_mfma<<<dim3(1024, 2), 256, 0, stream>>>(attnb, wos, b_out, out);
}

// Round 4
// 2196.736 us; speedup vs baseline: 2.8229x; 1.1512x over previous
//
#include <hip/hip_runtime.h>
#include <hip/hip_bf16.h>

typedef __hip_bfloat16 bf16;
typedef __attribute__((ext_vector_type(8))) short s16x8;
typedef __attribute__((ext_vector_type(4))) float f32x4;

#define SCALE 0.17677669529663687f

// ---- workspace offsets (bytes) ----
#define OFF_QKV   0ull            // bf16 [B][768][256][256] (rolled coords)
#define OFF_UL    201326592ull    // fp32 [B][128][256][256] squeeze out; later attn_sw bf16
#define OFF_CRU   268435456ull    // bf16 [B][512][256][256] cru pre-softmax
#define OFF_XT    OFF_CRU         // bf16 [131072][256] swizzled xT (dead before cru written)
#define OFF_POOL  402653184ull    // fp32 [2][512]
#define OFF_GNACC 402657280ull    // fp32 [2][16][2]
#define OFF_GNFIN 402657536ull    // fp32 mu/rstd + [64]=1/sum(gn_w)
#define OFF_SOFT  402658048ull    // fp32 [2][512]
#define OFF_WC    402662144ull    // fp32 [2][352][128]
#define OFF_WC2   403022592ull    // fp32 [64][256]
#define OFF_WQS   403088128ull    // bf16 [768][256] swizzled
#define OFF_WOS   403481344ull    // bf16 [256][256] swizzled
#define OFF_ATTN  OFF_UL          // bf16 [131072][256] swizzled attn out (final pix order)

__device__ __forceinline__ float b2f(bf16 v){ return __bfloat162float(v); }
__device__ __forceinline__ bf16  f2b(float v){ return __float2bfloat16(v); }
__device__ __forceinline__ ushort f2bu(float v){ bf16 b = __float2bfloat16(v); return *(ushort*)&b; }
__device__ __forceinline__ uint pk2(float a, float b){ return (uint)f2bu(a) | ((uint)f2bu(b) << 16); }

__device__ __forceinline__ void gload16(const void* g, void* l){
  __builtin_amdgcn_global_load_lds((const __attribute__((address_space(1))) unsigned int*)g,
                                   (__attribute__((address_space(3))) unsigned int*)l, 16, 0, 0);
}

// ---------------- weight prep: CRU pack + bf16-swizzled wq/wo ----------------
__global__ void k_wprep(const float* __restrict__ gwc_w, const float* __restrict__ pwc1,
                        const float* __restrict__ pwc2, const float* __restrict__ w_qkv,
                        const float* __restrict__ w_out, float* __restrict__ Wc,
                        float* __restrict__ Wc2, char* __restrict__ wqs, char* __restrict__ wos)
{
  int idx = blockIdx.x * 256 + threadIdx.x;
  if (idx < 90112){
    int c = idx & 127;
    int gk = idx >> 7;       // g*352 + k
    int g = gk / 352, k = gk - g * 352;
    int ch = g * 128 + c;
    Wc[idx] = (k < 288) ? gwc_w[(size_t)ch * 288 + k] : pwc1[ch * 64 + (k - 288)];
  } else if (idx < 106496){
    int j = idx - 90112;
    int k = j >> 8, c = j & 255;
    Wc2[j] = (c < 192) ? pwc2[c * 64 + k] : (k == (c - 192) ? 1.f : 0.f);
  } else if (idx < 303104){
    int j = idx - 106496;
    int n = j >> 8, k = j & 255;
    *(ushort*)(wqs + (size_t)n * 512 + ((k * 2) ^ ((n & 7) << 4))) = f2bu(w_qkv[n * 256 + k]);
  } else if (idx < 368640){
    int j = idx - 303104;
    int n = j >> 8, k = j & 255;
    *(ushort*)(wos + (size_t)n * 512 + ((k * 2) ^ ((n & 7) << 4))) = f2bu(w_out[n * 256 + k]);
  }
}

// ---------------- xT: x fp32 [ch][pix] -> bf16 [rolled pix][ch], XOR-swizzled ----
__global__ __launch_bounds__(256) void k_xt(const float* __restrict__ x, char* __restrict__ xt)
{
  __shared__ ushort Ls[64][66];
  int t = threadIdx.x;
  int jt = blockIdx.x;        // 0..3 (64-wide j tile)
  int i  = blockIdx.y;        // 0..255
  int zc = blockIdx.z;        // b*4 + ch-tile
  int ct = zc & 3, b = zc >> 2;
  int ch0 = ct * 64, j0 = jt * 64;
  for (int e = t; e < 4096; e += 256){
    int ch = e >> 6, jj = e & 63;
    Ls[ch][jj] = f2bu(x[(((size_t)(b * 256 + ch0 + ch)) << 16) + (i << 8) + j0 + jj]);
  }
  __syncthreads();
  int ri = (i - 4) & 255;
  #pragma unroll
  for (int s = 0; s < 2; s++){
    int id = s * 256 + t;
    int jj = id >> 3, blk = id & 7;
    int rj = (j0 + jj - 4) & 255;
    int m = (b << 16) + (ri << 8) + rj;
    ushort u0 = Ls[blk*8+0][jj], u1 = Ls[blk*8+1][jj], u2 = Ls[blk*8+2][jj], u3 = Ls[blk*8+3][jj];
    ushort u4 = Ls[blk*8+4][jj], u5 = Ls[blk*8+5][jj], u6 = Ls[blk*8+6][jj], u7 = Ls[blk*8+7][jj];
    uint4 pkv;
    pkv.x = (uint)u0 | ((uint)u1 << 16);
    pkv.y = (uint)u2 | ((uint)u3 << 16);
    pkv.z = (uint)u4 | ((uint)u5 << 16);
    pkv.w = (uint)u6 | ((uint)u7 << 16);
    size_t byte = (size_t)m * 512 + (((ch0 + blk * 8) * 2) ^ ((m & 7) << 4));
    *(uint4*)(xt + byte) = pkv;
  }
}

// ---------------- K1: qkv = xT @ wq^T + b via MFMA bf16 ----------------
__global__ __launch_bounds__(256) void k_qkv_mfma(
    const char* __restrict__ xt, const char* __restrict__ wq,
    const float* __restrict__ bias, bf16* __restrict__ qkv)
{
  __shared__ char sm[32768];
  int t = threadIdx.x;
  int l = t & 63, w = t >> 6;
  int ln = l & 15, l4 = l >> 4;
  int m0 = blockIdx.x * 128, n0 = blockIdx.y * 128;
  int wm0 = (w >> 1) * 64, wn0 = (w & 1) * 64;
  f32x4 acc[4][4];
  #pragma unroll
  for (int a = 0; a < 4; a++)
    #pragma unroll
    for (int c = 0; c < 4; c++) acc[a][c] = (f32x4){0.f, 0.f, 0.f, 0.f};
  const char* gA = xt + (size_t)(m0 + w * 32 + (l >> 3)) * 512 + (l & 7) * 16;
  const char* gB = wq + (size_t)(n0 + w * 32 + (l >> 3)) * 512 + (l & 7) * 16;
  char* ldsA = sm + (w * 32) * 128;
  char* ldsB = sm + 16384 + (w * 32) * 128;
  for (int k0 = 0; k0 < 256; k0 += 64){
    #pragma unroll
    for (int c = 0; c < 4; c++){
      gload16(gA + (size_t)k0 * 2 + c * 4096, ldsA + c * 1024);
      gload16(gB + (size_t)k0 * 2 + c * 4096, ldsB + c * 1024);
    }
    __syncthreads();
    s16x8 af[4][2], bfr[4][2];
    #pragma unroll
    for (int mi = 0; mi < 4; mi++){
      int r = wm0 + mi * 16 + ln;
      int key = (r & 7) << 4;
      #pragma unroll
      for (int kk = 0; kk < 2; kk++)
        af[mi][kk] = *(const s16x8*)(sm + r * 128 + ((kk * 64 + l4 * 16) ^ key));
    }
    #pragma unroll
    for (int ni = 0; ni < 4; ni++){
      int r = wn0 + ni * 16 + ln;
      int key = (r & 7) << 4;
      #pragma unroll
      for (int kk = 0; kk < 2; kk++)
        bfr[ni][kk] = *(const s16x8*)(sm + 16384 + r * 128 + ((kk * 64 + l4 * 16) ^ key));
    }
    #pragma unroll
    for (int kk = 0; kk < 2; kk++)
      #pragma unroll
      for (int mi = 0; mi < 4; mi++)
        #pragma unroll
        for (int ni = 0; ni < 4; ni++)
          acc[mi][ni] = __builtin_amdgcn_mfma_f32_16x16x32_bf16(af[mi][kk], bfr[ni][kk], acc[mi][ni], 0, 0, 0);
    __syncthreads();
  }
  #pragma unroll
  for (int ni = 0; ni < 4; ni++){
    int n = n0 + wn0 + ni * 16 + ln;
    float bs = bias[n];
    #pragma unroll
    for (int mi = 0; mi < 4; mi++){
      int mb = m0 + wm0 + mi * 16 + l4 * 4;
      int b = mb >> 16, pix = mb & 65535;
      ushort4 pkv;
      pkv.x = f2bu(acc[mi][ni].x + bs);
      pkv.y = f2bu(acc[mi][ni].y + bs);
      pkv.z = f2bu(acc[mi][ni].z + bs);
      pkv.w = f2bu(acc[mi][ni].w + bs);
      *(ushort4*)((char*)qkv + (((size_t)(b * 768 + n)) << 17) + pix * 2) = pkv;
    }
  }
}

// ---------------- K2a: GroupNorm partial stats over Q slice ----------------
__global__ __launch_bounds__(256) void k_gn_stats(const bf16* __restrict__ qkv,
                                                  float* __restrict__ acc)
{
  int blk = blockIdx.x;            // (b*16+g)*8 + s
  int s = blk & 7, bg = blk >> 3;
  int g = bg & 15, b = bg >> 4;
  int t = threadIdx.x;
  float sum = 0.f, sq = 0.f;
  for (int ch = 0; ch < 16; ch++){
    const bf16* base = qkv + (((size_t)(b * 768 + g * 16 + ch)) << 16) + s * 8192;
    for (int p = t; p < 8192; p += 256){
      float v = b2f(base[p]);
      sum += v; sq += v * v;
    }
  }
  __shared__ float rs[256], rq[256];
  rs[t] = sum; rq[t] = sq; __syncthreads();
  for (int st = 128; st > 0; st >>= 1){
    if (t < st){ rs[t] += rs[t + st]; rq[t] += rq[t + st]; }
    __syncthreads();
  }
  if (t == 0){
    atomicAdd(&acc[bg * 2], rs[0]);
    atomicAdd(&acc[bg * 2 + 1], rq[0]);
  }
}

__global__ __launch_bounds__(256) void k_gn_final(const float* __restrict__ acc,
                                                  const float* __restrict__ gn_w,
                                                  float* __restrict__ fin)
{
  __shared__ float red[256];
  int t = threadIdx.x;
  red[t] = gn_w[t]; __syncthreads();
  for (int st = 128; st > 0; st >>= 1){
    if (t < st) red[t] += red[t + st];
    __syncthreads();
  }
  if (t == 0) fin[64] = 1.0f / red[0];
  if (t < 32){
    const float Ninv = 1.0f / 1048576.0f;
    float mu = acc[t * 2] * Ninv;
    float var = acc[t * 2 + 1] * Ninv - mu * mu;
    fin[t * 2] = mu;
    fin[t * 2 + 1] = 1.0f / sqrtf(var + 1e-5f);
  }
}

// ---------------- K2b: SRU apply in-place on Q slice ----------------
__global__ __launch_bounds__(256) void k_sru(bf16* __restrict__ qkv,
    const float* __restrict__ fin, const float* __restrict__ gn_w,
    const float* __restrict__ gn_b)
{
  int idx = blockIdx.x * 256 + threadIdx.x;     // b(2)*c(128)*pix(65536)
  int pix = idx & 65535;
  int bc = idx >> 16;
  int c = bc & 127, b = bc >> 7;
  size_t i1 = (((size_t)(b * 768 + c)) << 16) + pix;
  size_t i2 = (((size_t)(b * 768 + c + 128)) << 16) + pix;
  float x1 = b2f(qkv[i1]);
  float x2 = b2f(qkv[i2]);
  int g1 = c >> 4, g2 = (c + 128) >> 4;
  float mu1 = fin[(b * 16 + g1) * 2], rs1 = fin[(b * 16 + g1) * 2 + 1];
  float mu2 = fin[(b * 16 + g2) * 2], rs2 = fin[(b * 16 + g2) * 2 + 1];
  float invs = fin[64];
  float w1c = gn_w[c], w2c = gn_w[c + 128];
  float gnx1 = (x1 - mu1) * rs1 * w1c + gn_b[c];
  float gnx2 = (x2 - mu2) * rs2 * w2c + gn_b[c + 128];
  float rw1 = 1.0f / (1.0f + __expf(-gnx1 * (w1c * invs)));
  float rw2 = 1.0f / (1.0f + __expf(-gnx2 * (w2c * invs)));
  float a1 = rw1 > 0.5f ? 1.0f : rw1, a2 = rw1 > 0.5f ? 0.0f : rw1;
  float b1 = rw2 > 0.5f ? 1.0f : rw2, b2v = rw2 > 0.5f ? 0.0f : rw2;
  qkv[i1] = f2b(a1 * x1 + b2v * x2);
  qkv[i2] = f2b(b1 * x2 + a2 * x1);
}

// ---------------- K3a: squeeze 1x1 convs on K slice -> ul ----------------
__global__ __launch_bounds__(256) void k_squeeze(const bf16* __restrict__ qkv,
    const float* __restrict__ sq1, const float* __restrict__ sq2,
    float* __restrict__ ul)
{
  __shared__ float in_s[128][65];
  int p0 = blockIdx.x * 64;
  int b = p0 >> 16, pl0 = p0 & 65535;
  int t = threadIdx.x;
  int pp = t & 63, og = t >> 6;      // og in 0..3, 16 outputs each
  for (int e = t; e < 8192; e += 256){
    int ch = e >> 6, px = e & 63;
    in_s[ch][px] = b2f(qkv[(((size_t)(b * 768 + 256 + ch)) << 16) + pl0 + px]);
  }
  __syncthreads();
  {
    float acc[16] = {};
    for (int i = 0; i < 128; i++){
      float v = in_s[i][pp];
      #pragma unroll
      for (int o = 0; o < 16; o++) acc[o] += sq1[(og * 16 + o) * 128 + i] * v;
    }
    #pragma unroll
    for (int o = 0; o < 16; o++)
      ul[(((size_t)(b * 128 + og * 16 + o)) << 16) + pl0 + pp] = acc[o];
  }
  __syncthreads();
  for (int e = t; e < 8192; e += 256){
    int ch = e >> 6, px = e & 63;
    in_s[ch][px] = b2f(qkv[(((size_t)(b * 768 + 384 + ch)) << 16) + pl0 + px]);
  }
  __syncthreads();
  {
    float acc[16] = {};
    for (int i = 0; i < 128; i++){
      float v = in_s[i][pp];
      #pragma unroll
      for (int o = 0; o < 16; o++) acc[o] += sq2[(og * 16 + o) * 128 + i] * v;
    }
    #pragma unroll
    for (int o = 0; o < 16; o++)
      ul[(((size_t)(b * 128 + 64 + og * 16 + o)) << 16) + pl0 + pp] = acc[o];
  }
}

// ---------------- K3b: CRU as GEMM (fp32) ----------------
__global__ __launch_bounds__(256) void k_cru_gemm(
    const float* __restrict__ ul, const float* __restrict__ Wmat,
    const float* __restrict__ gwc_b, bf16* __restrict__ cru, int mode)
{
  __shared__ float As[16][132];   // [kk][px]
  __shared__ float Bs[16][132];   // [kk][ch]
  int t = threadIdx.x;
  int tx = t & 15, ty = t >> 4;
  int tile = blockIdx.x;          // 32 row-tiles x 16 col-tiles
  int yT = blockIdx.y;
  int b = blockIdx.z;
  int tr = tile >> 4, tc = tile & 15;
  int ty0 = tr * 8, tx0 = tc * 16;
  int K = (mode == 0) ? 352 : 64;
  const float* W = (mode == 0) ? (Wmat + yT * 352 * 128) : Wmat;
  int wstride = (mode == 0) ? 128 : 256;
  int wcol0 = (mode == 0) ? 0 : yT * 128;
  float acc[8][8] = {};
  for (int k0 = 0; k0 < K; k0 += 16){
    #pragma unroll
    for (int l = 0; l < 8; l++){
      int e = t + l * 256;
      int mm = e & 127, kk = e >> 7;
      int k = k0 + kk;
      int py = mm >> 4, pxx = mm & 15;
      float v;
      if (mode == 0){
        int i, dy, dx;
        if (k < 288){
          i = k / 9; int r9 = k - i * 9; dy = r9 / 3; dx = r9 - dy * 3;
          i += yT * 32;
        } else { i = k - 288; dy = 1; dx = 1; }
        int gy = ty0 + py + dy - 1, gx = tx0 + pxx + dx - 1;
        v = (gy >= 0 && gy < 256 && gx >= 0 && gx < 256)
              ? ul[(((size_t)(b * 128 + i)) << 16) + (gy << 8) + gx] : 0.f;
      } else {
        v = ul[(((size_t)(b * 128 + 64 + k)) << 16) + ((ty0 + py) << 8) + tx0 + pxx];
      }
      As[kk][mm] = v;
    }
    #pragma unroll
    for (int l = 0; l < 8; l++){
      int e = t + l * 256;
      int nn = e & 127, kk = e >> 7;
      Bs[kk][nn] = W[(size_t)(k0 + kk) * wstride + wcol0 + nn];
    }
    __syncthreads();
    #pragma unroll
    for (int kk = 0; kk < 16; kk++){
      float4 a0 = *(const float4*)&As[kk][ty * 4];
      float4 a1 = *(const float4*)&As[kk][64 + ty * 4];
      float4 b0 = *(const float4*)&Bs[kk][tx * 4];
      float4 b1 = *(const float4*)&Bs[kk][64 + tx * 4];
      float av[8] = {a0.x,a0.y,a0.z,a0.w,a1.x,a1.y,a1.z,a1.w};
      float bv[8] = {b0.x,b0.y,b0.z,b0.w,b1.x,b1.y,b1.z,b1.w};
      #pragma unroll
      for (int r = 0; r < 8; r++)
        #pragma unroll
        for (int c = 0; c < 8; c++) acc[r][c] += av[r] * bv[c];
    }
    __syncthreads();
  }
  #pragma unroll
  for (int r = 0; r < 8; r++){
    int mr = (r < 4) ? (ty * 4 + r) : (64 + ty * 4 + r - 4);
    int py = mr >> 4, pxx = mr & 15;
    int gpix = ((ty0 + py) << 8) + tx0 + pxx;
    #pragma unroll
    for (int c = 0; c < 8; c++){
      int nc = (c < 4) ? (tx * 4 + c) : (64 + tx * 4 + c - 4);
      int ch; float bv;
      if (mode == 0){ ch = yT * 128 + nc; bv = gwc_b[ch]; }
      else          { ch = 256 + yT * 128 + nc; bv = 0.f; }
      cru[(((size_t)(b * 512 + ch)) << 16) + gpix] = f2b(acc[r][c] + bv);
    }
  }
}

// ---------------- K3d: per-channel sums of cru ----------------
__global__ __launch_bounds__(256) void k_pool(const bf16* __restrict__ cru,
                                              float* __restrict__ pool)
{
  int bc = blockIdx.x;  // b*512+ch
  const ushort4* p4 = (const ushort4*)(cru + (((size_t)bc) << 16));
  int t = threadIdx.x;
  float s = 0.f;
  for (int i = t; i < 16384; i += 256){
    ushort4 u = p4[i];
    s += b2f(*(bf16*)&u.x) + b2f(*(bf16*)&u.y) + b2f(*(bf16*)&u.z) + b2f(*(bf16*)&u.w);
  }
  __shared__ float red[256];
  red[t] = s; __syncthreads();
  for (int st = 128; st > 0; st >>= 1){
    if (t < st) red[t] += red[t + st];
    __syncthreads();
  }
  if (t == 0) pool[bc] = red[0];
}

// ---------------- K3f: channel softmax of pooled means ----------------
__global__ __launch_bounds__(512) void k_pool_softmax(const float* __restrict__ pool,
                                                      float* __restrict__ s)
{
  __shared__ float red[512];
  int t = threadIdx.x;
  for (int b = 0; b < 2; b++){
    float v = pool[b * 512 + t] * (1.0f / 65536.0f);
    red[t] = v; __syncthreads();
    for (int st = 256; st > 0; st >>= 1){
      if (t < st) red[t] = fmaxf(red[t], red[t + st]);
      __syncthreads();
    }
    float m = red[0]; __syncthreads();
    float e = __expf(v - m);
    red[t] = e; __syncthreads();
    for (int st = 256; st > 0; st >>= 1){
      if (t < st) red[t] += red[t + st];
      __syncthreads();
    }
    float inv = 1.0f / red[0];
    __syncthreads();
    s[b * 512 + t] = e * inv;
  }
}

// ---------------- K3c: k = s1*out1 + s2*out2 -> K slice of qkv ----------------
__global__ __launch_bounds__(256) void k_cru_apply(const bf16* __restrict__ cru,
    const float* __restrict__ s, bf16* __restrict__ qkv)
{
  int idx = blockIdx.x * 256 + threadIdx.x;  // b*256ch*65536pix
  int pix = idx & 65535;
  int bc = idx >> 16;
  int c = bc & 255, b = bc >> 8;
  float v1 = b2f(cru[(((size_t)(b * 512 + c)) << 16) + pix]);
  float v2 = b2f(cru[(((size_t)(b * 512 + 256 + c)) << 16) + pix]);
  float kv = s[b * 512 + c] * v1 + s[b * 512 + 256 + c] * v2;
  qkv[(((size_t)(b * 768 + 256 + c)) << 16) + pix] = f2b(kv);
}

// ---------------- K4: windowed attention (coalesced, 4 windows/block) --------
// block = 256 thr: rows r=t>>5 (8), cols c=t&31 (32 contiguous). 1 head.
// grid: x=8 col-groups, y=32 row-bands, z=b*8+head.
__global__ __launch_bounds__(256, 3) void k_attn(const bf16* __restrict__ qkv,
    const float* __restrict__ rel_pos, char* __restrict__ attnb)
{
  __shared__ float kv_s[64 * 4 * 36];   // [jpix][win][36] fp32, two-phase K then V
  __shared__ float bias_s[225];
  int t = threadIdx.x;
  int wg = blockIdx.x, hw = blockIdx.y;
  int z = blockIdx.z;
  int head = z & 7, b = z >> 3;
  int r = t >> 5, c = t & 31;
  int win = c >> 3, pj = c & 7, pi = r;
  int i = hw * 8 + r, j = wg * 32 + c;
  int pix = (i << 8) | j;
  int jpix = r * 8 + pj;                // window-local pixel id of this thread
  int lrow = ((jpix << 2) | win) * 36;  // this thread's LDS row base
  size_t base = ((size_t)(b * 768)) << 16;
  int h32 = head * 32;

  for (int e = t; e < 225; e += 256) bias_s[e] = rel_pos[head * 225 + e];

  // Q into regs, K into LDS (float4-staged writes)
  float q[32];
  #pragma unroll
  for (int d4 = 0; d4 < 8; d4++){
    float kv0 = b2f(qkv[base + (((size_t)(256 + h32 + d4*4+0)) << 16) + pix]);
    float kv1 = b2f(qkv[base + (((size_t)(256 + h32 + d4*4+1)) << 16) + pix]);
    float kv2 = b2f(qkv[base + (((size_t)(256 + h32 + d4*4+2)) << 16) + pix]);
    float kv3 = b2f(qkv[base + (((size_t)(256 + h32 + d4*4+3)) << 16) + pix]);
    *(float4*)&kv_s[lrow + d4*4] = make_float4(kv0, kv1, kv2, kv3);
    q[d4*4+0] = b2f(qkv[base + (((size_t)(h32 + d4*4+0)) << 16) + pix]);
    q[d4*4+1] = b2f(qkv[base + (((size_t)(h32 + d4*4+1)) << 16) + pix]);
    q[d4*4+2] = b2f(qkv[base + (((size_t)(h32 + d4*4+2)) << 16) + pix]);
    q[d4*4+3] = b2f(qkv[base + (((size_t)(h32 + d4*4+3)) << 16) + pix]);
  }
  __syncthreads();

  bool mH = (hw == 31), mW = (wg == 7 && win == 3);
  float sim[64];
  float mx = -1e30f;
  #pragma unroll 4
  for (int jp = 0; jp < 64; jp++){
    const float4* kp = (const float4*)&kv_s[((jp << 2) | win) * 36];
    float sv = 0.f;
    #pragma unroll
    for (int d4 = 0; d4 < 8; d4++){
      float4 kk = kp[d4];
      sv += q[d4*4+0]*kk.x + q[d4*4+1]*kk.y + q[d4*4+2]*kk.z + q[d4*4+3]*kk.w;
    }
    int ji = jp >> 3, jj = jp & 7;
    sv = sv * SCALE + bias_s[(pi - ji + 7) * 15 + (pj - jj + 7)];
    bool masked = (mH && ((pi < 4) != (ji < 4))) || (mW && ((pj < 4) != (jj < 4)));
    sv = masked ? -1e30f : sv;
    sim[jp] = sv;
    mx = fmaxf(mx, sv);
  }
  float sum = 0.f;
  #pragma unroll
  for (int jp = 0; jp < 64; jp++){
    float e = __expf(sim[jp] - mx);
    sim[jp] = e; sum += e;
  }
  float inv = 1.0f / sum;
  __syncthreads();

  // overwrite LDS with V
  #pragma unroll
  for (int d4 = 0; d4 < 8; d4++){
    float v0 = b2f(qkv[base + (((size_t)(512 + h32 + d4*4+0)) << 16) + pix]);
    float v1 = b2f(qkv[base + (((size_t)(512 + h32 + d4*4+1)) << 16) + pix]);
    float v2 = b2f(qkv[base + (((size_t)(512 + h32 + d4*4+2)) << 16) + pix]);
    float v3 = b2f(qkv[base + (((size_t)(512 + h32 + d4*4+3)) << 16) + pix]);
    *(float4*)&kv_s[lrow + d4*4] = make_float4(v0, v1, v2, v3);
  }
  __syncthreads();

  float o[32] = {};
  #pragma unroll 4
  for (int jp = 0; jp < 64; jp++){
    float p = sim[jp] * inv;
    const float4* vp = (const float4*)&kv_s[((jp << 2) | win) * 36];
    #pragma unroll
    for (int d4 = 0; d4 < 8; d4++){
      float4 vv = vp[d4];
      o[d4*4+0] += p * vv.x;
      o[d4*4+1] += p * vv.y;
      o[d4*4+2] += p * vv.z;
      o[d4*4+3] += p * vv.w;
    }
  }

  // write at rolled-back pixel, XOR-swizzled row for MFMA proj staging
  int om = (b << 16) + (((i + 4) & 255) << 8) + ((j + 4) & 255);
  size_t rb = (size_t)om * 512;
  int key = (om & 7) << 4;
  #pragma unroll
  for (int d0 = 0; d0 < 32; d0 += 8){
    uint4 pkv;
    pkv.x = pk2(o[d0+0], o[d0+1]);
    pkv.y = pk2(o[d0+2], o[d0+3]);
    pkv.z = pk2(o[d0+4], o[d0+5]);
    pkv.w = pk2(o[d0+6], o[d0+7]);
    *(uint4*)(attnb + rb + ((head * 64 + d0 * 2) ^ key)) = pkv;
  }
}

// ---------------- K6: out = attn @ w_out^T + b_out via MFMA ----------------
__global__ __launch_bounds__(256) void k_proj_mfma(
    const char* __restrict__ at, const char* __restrict__ wo,
    const float* __restrict__ bias, float* __restrict__ outp)
{
  __shared__ char sm[32768];
  int t = threadIdx.x;
  int l = t & 63, w = t >> 6;
  int ln = l & 15, l4 = l >> 4;
  int m0 = blockIdx.x * 128, n0 = blockIdx.y * 128;
  int wm0 = (w >> 1) * 64, wn0 = (w & 1) * 64;
  f32x4 acc[4][4];
  #pragma unroll
  for (int a = 0; a < 4; a++)
    #pragma unroll
    for (int c = 0; c < 4; c++) acc[a][c] = (f32x4){0.f, 0.f, 0.f, 0.f};
  const char* gA = at + (size_t)(m0 + w * 32 + (l >> 3)) * 512 + (l & 7) * 16;
  const char* gB = wo + (size_t)(n0 + w * 32 + (l >> 3)) * 512 + (l & 7) * 16;
  char* ldsA = sm + (w * 32) * 128;
  char* ldsB = sm + 16384 + (w * 32) * 128;
  for (int k0 = 0; k0 < 256; k0 += 64){
    #pragma unroll
    for (int c = 0; c < 4; c++){
      gload16(gA + (size_t)k0 * 2 + c * 4096, ldsA + c * 1024);
      gload16(gB + (size_t)k0 * 2 + c * 4096, ldsB + c * 1024);
    }
    __syncthreads();
    s16x8 af[4][2], bfr[4][2];
    #pragma unroll
    for (int mi = 0; mi < 4; mi++){
      int r = wm0 + mi * 16 + ln;
      int key = (r & 7) << 4;
      #pragma unroll
      for (int kk = 0; kk < 2; kk++)
        af[mi][kk] = *(const s16x8*)(sm + r * 128 + ((kk * 64 + l4 * 16) ^ key));
    }
    #pragma unroll
    for (int ni = 0; ni < 4; ni++){
      int r = wn0 + ni * 16 + ln;
      int key = (r & 7) << 4;
      #pragma unroll
      for (int kk = 0; kk < 2; kk++)
        bfr[ni][kk] = *(const s16x8*)(sm + 16384 + r * 128 + ((kk * 64 + l4 * 16) ^ key));
    }
    #pragma unroll
    for (int kk = 0; kk < 2; kk++)
      #pragma unroll
      for (int mi = 0; mi < 4; mi++)
        #pragma unroll
        for (int ni = 0; ni < 4; ni++)
          acc[mi][ni] = __builtin_amdgcn_mfma_f32_16x16x32_bf16(af[mi][kk], bfr[ni][kk], acc[mi][ni], 0, 0, 0);
    __syncthreads();
  }
  #pragma unroll
  for (int ni = 0; ni < 4; ni++){
    int n = n0 + wn0 + ni * 16 + ln;
    float bs = bias[n];
    #pragma unroll
    for (int mi = 0; mi < 4; mi++){
      int mb = m0 + wm0 + mi * 16 + l4 * 4;
      int b = mb >> 16, pix = mb & 65535;
      float4 v;
      v.x = acc[mi][ni].x + bs;
      v.y = acc[mi][ni].y + bs;
      v.z = acc[mi][ni].z + bs;
      v.w = acc[mi][ni].w + bs;
      *(float4*)(outp + (((size_t)(b * 256 + n)) << 16) + pix) = v;
    }
  }
}

extern "C" void kernel_launch(void* const* d_in, const int* in_sizes, int n_in,
                              void* d_out, int out_size, void* d_ws, size_t ws_size,
                              hipStream_t stream) {
  const float* x       = (const float*)d_in[0];
  const float* w_qkv   = (const float*)d_in[1];
  const float* b_qkv   = (const float*)d_in[2];
  const float* rel_pos = (const float*)d_in[3];
  const float* gn_w    = (const float*)d_in[4];
  const float* gn_b    = (const float*)d_in[5];
  const float* sq1     = (const float*)d_in[6];
  const float* sq2     = (const float*)d_in[7];
  const float* gwc_w   = (const float*)d_in[8];
  const float* gwc_b   = (const float*)d_in[9];
  const float* pwc1    = (const float*)d_in[10];
  const float* pwc2    = (const float*)d_in[11];
  const float* w_out   = (const float*)d_in[12];
  const float* b_out   = (const float*)d_in[13];
  float* out = (float*)d_out;

  char* ws = (char*)d_ws;
  bf16*  qkv   = (bf16*)(ws + OFF_QKV);
  float* ul    = (float*)(ws + OFF_UL);
  bf16*  cru   = (bf16*)(ws + OFF_CRU);
  char*  xt    = ws + OFF_XT;
  float* pool  = (float*)(ws + OFF_POOL);
  float* gnacc = (float*)(ws + OFF_GNACC);
  float* gnfin = (float*)(ws + OFF_GNFIN);
  float* smax  = (float*)(ws + OFF_SOFT);
  float* Wc    = (float*)(ws + OFF_WC);
  float* Wc2   = (float*)(ws + OFF_WC2);
  char*  wqs   = ws + OFF_WQS;
  char*  wos   = ws + OFF_WOS;
  char*  attnb = ws + OFF_ATTN;

  hipMemsetAsync(ws + OFF_GNACC, 0, 256, stream);
  k_wprep<<<1440, 256, 0, stream>>>(gwc_w, pwc1, pwc2, w_qkv, w_out, Wc, Wc2, wqs, wos);
  k_xt<<<dim3(4, 256, 8), 256, 0, stream>>>(x, xt);
  k_qkv_mfma<<<dim3(1024, 6), 256, 0, stream>>>(xt, wqs, b_qkv, qkv);
  k_gn_stats<<<256, 256, 0, stream>>>(qkv, gnacc);
  k_gn_final<<<1, 256, 0, stream>>>(gnacc, gn_w, gnfin);
  k_sru<<<65536, 256, 0, stream>>>(qkv, gnfin, gn_w, gn_b);
  k_squeeze<<<2048, 256, 0, stream>>>(qkv, sq1, sq2, ul);
  k_cru_gemm<<<dim3(512, 2, 2), 256, 0, stream>>>(ul, Wc, gwc_b, cru, 0);
  k_cru_gemm<<<dim3(512, 2, 2), 256, 0, stream>>>(ul, Wc2, gwc_b, cru, 1);
  k_pool<<<1024, 256, 0, stream>>>(cru, pool);
  k_pool_softmax<<<1, 512, 0, stream>>>(pool, smax);
  k_cru_apply<<<131072, 256, 0, stream>>>(cru, smax, qkv);
  k_attn<<<dim3(8, 32, 16), 256, 0, stream>>>(qkv, rel_pos, attnb);
  k_proj_mfma<<<dim3(1024, 2), 256, 0, stream>>>(attnb, wos, b_out, out);
}